// Round 13
// baseline (335.333 us; speedup 1.0000x reference)
//
#include <hip/hip_runtime.h>
#include <hip/hip_bf16.h>

// ---------------- problem constants ----------------
#define Bb   2
#define Cc   256
#define Nn   1024
#define Mm   65536
#define VROWS 272         // 256 desc + 3 coords + 1 weight + ones + 11 pad
#define MSTEP 32

// workspace byte offsets (fixed part)
#define SCL_OFF  0L                               // B*M f32           (0.5 MB)
#define TMC_OFF  524288L                          // B*M*C bf16        (67 MB)   K: [b][m][c]
#define TCM_OFF  67633152L                        // B*272*M bf16      (71.3 MB) V: [b][row][m]
#define SNC_OFF  138936320L                       // B*N*C bf16        (1 MB)    Q^T: [b][n][c]
#define PART_OFF 139984896L                       // B*MCn*N*272 bf16  (MCn runtime)
// stats partials live in the part region (consumed before k_main writes part)
#define PS_OFF   PART_OFF                         // [B][4][M] f32 sums   (2 MB)
#define PS2_OFF  (PART_OFF + 2097152L)            // [B][4][M] f32 sumsq  (2 MB)

// output float offsets
#define O_COORD 0L
#define O_W     6144L
#define O_DESC  8192L
#define O_P2D   532480L
#define O_VALID 536576L
#define O_MAXSM 538624L

using f32x4 = __attribute__((ext_vector_type(4))) float;
using s16x8 = __attribute__((ext_vector_type(8))) short;

__device__ inline unsigned short f2bf(float x) {
    union { float f; unsigned int u; } v; v.f = x;
    unsigned int r = v.u + 0x7FFFu + ((v.u >> 16) & 1u);   // RNE
    return (unsigned short)(r >> 16);
}
__device__ inline float bf2f(unsigned short u) {
    union { unsigned int u; float f; } v; v.u = ((unsigned int)u) << 16;
    return v.f;
}
__device__ inline float exp2v(float x) {
    float r; asm("v_exp_f32 %0, %1" : "=v"(r) : "v"(x)); return r;
}
__device__ inline unsigned int cvtpk(float lo, float hi) {
    unsigned int r;
    asm("v_cvt_pk_bf16_f32 %0, %1, %2" : "=v"(r) : "v"(lo), "v"(hi));
    return r;
}

__device__ inline void gld_lds16(const unsigned short* g, unsigned short* l) {
    __builtin_amdgcn_global_load_lds(
        (const __attribute__((address_space(1))) unsigned int*)g,
        (__attribute__((address_space(3))) unsigned int*)l, 16, 0, 0);
}

// ------- prep A: tgt_desc f32 -> tmc bf16 [b][m][c] + tcm bf16 [b][c][m],
//                 plus per-(c-block, m) partial sums for the column stats -------
__global__ void k_prep_tgt(const float* __restrict__ tgt,
                           unsigned short* __restrict__ tmc,
                           unsigned short* __restrict__ tcm,
                           float* __restrict__ ps,
                           float* __restrict__ ps2) {
    __shared__ float lds[64][65];
    __shared__ float sm[4][64], sm2[4][64];
    int b = blockIdx.z, cy = blockIdx.y, c0 = cy * 64;
    long m0 = (long)blockIdx.x * 64;
    int ty = threadIdx.x >> 6, tx = threadIdx.x & 63;
    float s = 0.f, s2 = 0.f;
    #pragma unroll
    for (int k = 0; k < 16; ++k) {
        int ci = 4 * k + ty;
        float v = tgt[((long)b * Cc + c0 + ci) * Mm + m0 + tx];
        lds[ci][tx] = v;
        s += v; s2 += v * v;
        tcm[((long)b * VROWS + c0 + ci) * Mm + m0 + tx] = f2bf(v);
    }
    sm[ty][tx] = s; sm2[ty][tx] = s2;
    __syncthreads();
    #pragma unroll
    for (int k = 0; k < 16; ++k) {
        int mi = 4 * k + ty;
        tmc[((long)b * Mm + m0 + mi) * Cc + c0 + tx] = f2bf(lds[tx][mi]);
    }
    if (ty == 0) {
        long o = ((long)b * 4 + cy) * Mm + m0 + tx;
        ps[o]  = (sm[0][tx] + sm[1][tx]) + (sm[2][tx] + sm[3][tx]);
        ps2[o] = (sm2[0][tx] + sm2[1][tx]) + (sm2[2][tx] + sm2[3][tx]);
    }
}

// ------- prep B: finish stats -> scl; write coords/weights/ones rows of V -------
__global__ void k_stats(const float* __restrict__ ps,
                        const float* __restrict__ ps2,
                        const float* __restrict__ coords,
                        const float* __restrict__ weights,
                        float* __restrict__ scl,
                        unsigned short* __restrict__ tcm) {
    int b = blockIdx.y;
    long m = (long)blockIdx.x * 256 + threadIdx.x;
    float s = 0.f, s2 = 0.f;
    #pragma unroll
    for (int k = 0; k < 4; ++k) {
        long o = ((long)b * 4 + k) * Mm + m;
        s += ps[o]; s2 += ps2[o];
    }
    float var = fmaxf((s2 - s * s * (1.0f / Cc)) * (1.0f / (Cc - 1)), 1e-20f);
    scl[(long)b * Mm + m] = 1.4426950408889634f * rsqrtf(var) * (1.0f / (Cc * 0.01f));
    unsigned short* vrow = tcm + ((long)b * VROWS + 256) * Mm + m;
    #pragma unroll
    for (int i = 0; i < 3; ++i) vrow[(long)i * Mm] = f2bf(coords[((long)b * 3 + i) * Mm + m]);
    vrow[3L * Mm] = f2bf(weights[(long)b * Mm + m]);
    vrow[4L * Mm] = 0x3F80;   // ones row (channel 260): Z comes out of the PV MFMA
    #pragma unroll
    for (int i = 5; i < 16; ++i) vrow[(long)i * Mm] = 0;
}

// ------- prep C: src_desc_norm f32 -> snc bf16 [b][n][c] -------
__global__ void k_prep_src(const float* __restrict__ src, unsigned short* __restrict__ snc) {
    __shared__ float lds[64][65];
    int b = blockIdx.z, c0 = blockIdx.y * 64, n0 = blockIdx.x * 64;
    int ty = threadIdx.x >> 6, tx = threadIdx.x & 63;
    #pragma unroll
    for (int k = 0; k < 16; ++k)
        lds[4 * k + ty][tx] = src[((long)b * Cc + c0 + 4 * k + ty) * Nn + n0 + tx];
    __syncthreads();
    #pragma unroll
    for (int k = 0; k < 16; ++k) {
        int ni = 4 * k + ty;
        snc[((long)b * Nn + n0 + ni) * Cc + c0 + tx] = f2bf(lds[tx][ni]);
    }
}

// ------- main fused kernel: 64 n per wave, PV(s-1) pipelined -------
// 4 waves * 64 n = 256 n per block. Per iter: stage(s+1); PV(s-1) (pbuf and V
// written before last barrier -> zero-wait, 68 independent MFMAs); QK(s) ->
// exp -> pack -> pbuf[s&1]. PV and QK chains are independent so the scheduler
// keeps the matrix pipe fed while exp/pack VALU fills the gaps.
__global__ __launch_bounds__(256, 1) void k_main(const unsigned short* __restrict__ tmc,
                                                 const unsigned short* __restrict__ tcm,
                                                 const unsigned short* __restrict__ snc,
                                                 const float* __restrict__ scl,
                                                 unsigned short* __restrict__ part,
                                                 float* __restrict__ zp,
                                                 float* __restrict__ pp,
                                                 int mcn) {
    __shared__ __align__(16) unsigned short kb[2][8192];            // 32 KB
    __shared__ __align__(16) unsigned short vb[3][8704];            // 51 KB
    __shared__ __align__(16) unsigned short pbuf[2][4][4][16][40];  // 40 KB

    int w = threadIdx.x >> 6, lane = threadIdx.x & 63;
    int l15 = lane & 15, lg = lane >> 4;
    int b = blockIdx.z, nt = blockIdx.y, mc = blockIdx.x;
    int nb = nt * 256 + w * 64;
    int mchunk = Mm / mcn;
    int nit = mchunk / MSTEP;
    long mbase = (long)mc * mchunk;

    // Q^T B-fragments for 4 n-subtiles (permanent registers, 128 VGPR)
    s16x8 qf[4][8];
    #pragma unroll
    for (int st = 0; st < 4; ++st) {
        const unsigned short* qp = snc + ((long)b * Nn + nb + st * 16 + l15) * Cc + lg * 8;
        #pragma unroll
        for (int cc = 0; cc < 8; ++cc) qf[st][cc] = *(const s16x8*)(qp + cc * 32);
    }

    f32x4 acc[4][17];
    #pragma unroll
    for (int st = 0; st < 4; ++st)
        #pragma unroll
        for (int t = 0; t < 17; ++t) acc[st][t] = (f32x4){0.f, 0.f, 0.f, 0.f};
    float pmax[4] = {0.f, 0.f, 0.f, 0.f};

    // ---- staging source pointers (per-lane, pre-swizzled) ----
    const unsigned short* tmcb = tmc + (long)b * Mm * Cc;
    const unsigned short* tcmb = tcm + (long)b * VROWS * (long)Mm;
    const unsigned short* ksrc[4];
    #pragma unroll
    for (int i = 0; i < 4; ++i) {
        int ins = w * 4 + i;                 // K instr 0..15, covers rows 2*ins, 2*ins+1
        int row = 2 * ins + (lane >> 5);
        int gs  = (lane & 31) ^ (row & 7);   // pre-swizzled 16B slot
        ksrc[i] = tmcb + (mbase + row) * Cc + gs * 8;
    }
    const unsigned short* vsrc[5];
    int vj = ((lane & 3) ^ ((lane >> 3) & 3)) * 8;   // chunk-XOR pre-swizzle
    #pragma unroll
    for (int i = 0; i < 5; ++i) {
        int ins = (i < 4) ? (w * 4 + i) : 16;
        int row = ins * 16 + (lane >> 2);
        vsrc[i] = tcmb + (long)row * Mm + mbase + vj;
    }

    const float* sclb = scl + (long)b * Mm;

    auto stage = [&](int kd_i, int vd_i) {
        unsigned short* kd = kb[kd_i];
        unsigned short* vd = vb[vd_i];
        #pragma unroll
        for (int i = 0; i < 4; ++i) gld_lds16(ksrc[i], kd + (w * 4 + i) * 512);
        #pragma unroll
        for (int i = 0; i < 4; ++i) gld_lds16(vsrc[i], vd + (w * 4 + i) * 512);
        if (w == 3) gld_lds16(vsrc[4], vd + 16 * 512);
        #pragma unroll
        for (int i = 0; i < 4; ++i) ksrc[i] += MSTEP * Cc;
        #pragma unroll
        for (int i = 0; i < 5; ++i) vsrc[i] += MSTEP;
    };

    int ksw = (l15 & 7) << 3;              // K read swizzle (elements)
    int vsw = (lg ^ ((l15 >> 1) & 3)) * 8; // V read chunk swizzle (elements)

    // PV for step sp (pbuf/V written before the last barrier -> no wait)
    auto pv_step = [&](int sp) {
        const unsigned short* vbc = vb[sp % 3];
        const unsigned short (*pr)[4][16][40] = pbuf[sp & 1];
        s16x8 pfA = *(const s16x8*)&pr[w][0][l15][lg * 8];
        s16x8 pfB = *(const s16x8*)&pr[w][1][l15][lg * 8];
        s16x8 pfC = *(const s16x8*)&pr[w][2][l15][lg * 8];
        s16x8 pfD = *(const s16x8*)&pr[w][3][l15][lg * 8];
        #pragma unroll
        for (int t = 0; t < 17; ++t) {
            s16x8 vf = *(const s16x8*)(vbc + (t * 16 + l15) * MSTEP + vsw);
            acc[0][t] = __builtin_amdgcn_mfma_f32_16x16x32_bf16(vf, pfA, acc[0][t], 0, 0, 0);
            acc[1][t] = __builtin_amdgcn_mfma_f32_16x16x32_bf16(vf, pfB, acc[1][t], 0, 0, 0);
            acc[2][t] = __builtin_amdgcn_mfma_f32_16x16x32_bf16(vf, pfC, acc[2][t], 0, 0, 0);
            acc[3][t] = __builtin_amdgcn_mfma_f32_16x16x32_bf16(vf, pfD, acc[3][t], 0, 0, 0);
        }
    };

    stage(0, 0);
    __syncthreads();

    for (int s = 0; s < nit; ++s) {
        if (s + 1 < nit) stage((s + 1) & 1, (s + 1) % 3);
        const unsigned short* kbc = kb[s & 1];
        long m0 = mbase + (long)s * MSTEP;
        float4 sc0 = *(const float4*)(sclb + m0 + lg * 4);
        float4 sc1 = *(const float4*)(sclb + m0 + 16 + lg * 4);

        // ---- PV(s-1): fully independent of QK(s); issues first ----
        if (s) pv_step(s - 1);

        // ---- QK(s): 2 m-subtiles x 4 n-subtiles -> pbuf[s&1] ----
        #pragma unroll
        for (int t = 0; t < 2; ++t) {
            f32x4 dA = (f32x4){0.f, 0.f, 0.f, 0.f};
            f32x4 dB = (f32x4){0.f, 0.f, 0.f, 0.f};
            f32x4 dC = (f32x4){0.f, 0.f, 0.f, 0.f};
            f32x4 dD = (f32x4){0.f, 0.f, 0.f, 0.f};
            const unsigned short* kr = kbc + (t * 16 + l15) * Cc;
            #pragma unroll
            for (int cc = 0; cc < 8; ++cc) {
                s16x8 kf = *(const s16x8*)(kr + ((cc * 32 + lg * 8) ^ ksw));
                dA = __builtin_amdgcn_mfma_f32_16x16x32_bf16(kf, qf[0][cc], dA, 0, 0, 0);
                dB = __builtin_amdgcn_mfma_f32_16x16x32_bf16(kf, qf[1][cc], dB, 0, 0, 0);
                dC = __builtin_amdgcn_mfma_f32_16x16x32_bf16(kf, qf[2][cc], dC, 0, 0, 0);
                dD = __builtin_amdgcn_mfma_f32_16x16x32_bf16(kf, qf[3][cc], dD, 0, 0, 0);
            }
            float4 sc = t ? sc1 : sc0;
            #pragma unroll
            for (int st = 0; st < 4; ++st) {
                f32x4 d = (st == 0) ? dA : (st == 1) ? dB : (st == 2) ? dC : dD;
                float p0 = exp2v(d.x * sc.x);
                float p1 = exp2v(d.y * sc.y);
                float p2 = exp2v(d.z * sc.z);
                float p3 = exp2v(d.w * sc.w);
                pmax[st] = fmaxf(pmax[st], fmaxf(fmaxf(p0, p1), fmaxf(p2, p3)));
                unsigned long long pk =
                    (unsigned long long)cvtpk(p0, p1) | ((unsigned long long)cvtpk(p2, p3) << 32);
                *(unsigned long long*)&pbuf[s & 1][w][st][l15][t * 16 + lg * 4] = pk;
            }
        }
        __syncthreads();
    }
    // tail: PV(nit-1)
    pv_step(nit - 1);

    // Z sits in acc[st][16].x on lanes lg==1 (channel 260 = ones row)
    #pragma unroll
    for (int st = 0; st < 4; ++st) {
        float pt = fmaxf(pmax[st], __shfl_xor(pmax[st], 16));
        pt = fmaxf(pt, __shfl_xor(pt, 32));
        long zi = ((long)(b * mcn + mc)) * Nn + nb + st * 16;
        if (lg == 1) zp[zi + l15] = acc[st][16].x;
        if (lane < 16) pp[zi + lane] = pt;
        unsigned short* po = part + (((long)(b * mcn + mc) * Nn) + nb + st * 16 + l15) * VROWS;
        #pragma unroll
        for (int t = 0; t < 17; ++t) {
            f32x4 a = acc[st][t];
            unsigned long long pk =
                (unsigned long long)cvtpk(a.x, a.y) | ((unsigned long long)cvtpk(a.z, a.w) << 32);
            *(unsigned long long*)&po[t * 16 + lg * 4] = pk;
        }
    }
}

// ------- epilogue: combine m-chunks, normalize, zn(descs), 2D projection, max_softmax -------
__global__ void k_epi(const unsigned short* __restrict__ part,
                      const float* __restrict__ zp,
                      const float* __restrict__ pp,
                      float* __restrict__ out,
                      int mcn) {
    int w = threadIdx.x >> 6, lane = threadIdx.x & 63;
    int bn = blockIdx.x * 4 + w;
    int b = bn >> 10, n = bn & 1023;

    float Z = 0.f, pm = 0.f;
    for (int mc = 0; mc < mcn; ++mc) {
        long zi = ((long)(b * mcn + mc)) * Nn + n;
        Z += zp[zi];
        pm = fmaxf(pm, pp[zi]);
    }
    float invZ = 1.0f / Z;

    float dv[4], s1 = 0.f, s2 = 0.f;
    #pragma unroll
    for (int k = 0; k < 4; ++k) {
        int c = lane + 64 * k;
        float s = 0.f;
        for (int mc = 0; mc < mcn; ++mc)
            s += bf2f(part[((long)(b * mcn + mc) * Nn + n) * VROWS + c]);
        float d = s * invZ;
        dv[k] = d; s1 += d; s2 += d * d;
    }
    #pragma unroll
    for (int off = 1; off < 64; off <<= 1) { s1 += __shfl_xor(s1, off); s2 += __shfl_xor(s2, off); }
    float mean = s1 * (1.0f / 256.0f);
    float var = fmaxf((s2 - 256.0f * mean * mean) * (1.0f / 255.0f), 1e-20f);
    float istd = 1.0f / sqrtf(var);
    #pragma unroll
    for (int k = 0; k < 4; ++k)
        out[O_DESC + ((long)b * Cc + lane + 64 * k) * Nn + n] = (dv[k] - mean) * istd;

    float ex = 0.f;
    if (lane < 4) {
        int c = 256 + lane;
        for (int mc = 0; mc < mcn; ++mc)
            ex += bf2f(part[((long)(b * mcn + mc) * Nn + n) * VROWS + c]);
        ex *= invZ;
    }
    float pc0 = __shfl(ex, 0), pc1 = __shfl(ex, 1), pc2 = __shfl(ex, 2), wv = __shfl(ex, 3);
    if (lane == 0) {
        out[O_COORD + ((long)b * 3 + 0) * Nn + n] = pc0;
        out[O_COORD + ((long)b * 3 + 1) * Nn + n] = pc1;
        out[O_COORD + ((long)b * 3 + 2) * Nn + n] = pc2;
        out[O_W + (long)b * Nn + n] = wv;
        const float cmin = 33.048f;                 // (256/2 - 0.5) * 0.2592
        out[O_P2D + ((long)b * Nn + n) * 2 + 0] = (cmin + pc1) * (1.0f / 0.2592f);
        out[O_P2D + ((long)b * Nn + n) * 2 + 1] = (cmin - pc0) * (1.0f / 0.2592f);
        out[O_VALID + (long)b * Nn + n] = 1.0f;
        atomicMax((unsigned int*)out + O_MAXSM + b, __float_as_uint(pm * invZ));
    }
}

extern "C" void kernel_launch(void* const* d_in, const int* in_sizes, int n_in,
                              void* d_out, int out_size, void* d_ws, size_t ws_size,
                              hipStream_t stream) {
    const float* tgt_coords  = (const float*)d_in[1];
    const float* tgt_weights = (const float*)d_in[3];
    const float* src_desc    = (const float*)d_in[5];
    const float* tgt_desc    = (const float*)d_in[6];

    char* ws = (char*)d_ws;
    float* scl           = (float*)(ws + SCL_OFF);
    unsigned short* tmc  = (unsigned short*)(ws + TMC_OFF);
    unsigned short* tcm  = (unsigned short*)(ws + TCM_OFF);
    unsigned short* snc  = (unsigned short*)(ws + SNC_OFF);
    unsigned short* part = (unsigned short*)(ws + PART_OFF);
    float* ps            = (float*)(ws + PS_OFF);
    float* ps2           = (float*)(ws + PS2_OFF);
    float* out           = (float*)d_out;

    // choose m-chunk count by available workspace: 32 chunks needs ~176 MB
    long need32 = PART_OFF + (long)Bb * 32 * Nn * VROWS * 2 + 2L * Bb * 32 * Nn * 4;
    int mcn = (ws_size >= (size_t)need32) ? 32 : 16;
    long zp_off = PART_OFF + (long)Bb * mcn * Nn * VROWS * 2;
    long pp_off = zp_off + (long)Bb * mcn * Nn * 4;
    float* zp = (float*)(ws + zp_off);
    float* pp = (float*)(ws + pp_off);

    k_prep_tgt<<<dim3(Mm / 64, Cc / 64, Bb), 256, 0, stream>>>(tgt_desc, tmc, tcm, ps, ps2);
    k_stats<<<dim3(Mm / 256, Bb), 256, 0, stream>>>(ps, ps2, tgt_coords, tgt_weights, scl, tcm);
    k_prep_src<<<dim3(Nn / 64, Cc / 64, Bb), 256, 0, stream>>>(src_desc, snc);
    k_main<<<dim3(mcn, Nn / 256, Bb), 256, 0, stream>>>(tmc, tcm, snc, scl, part, zp, pp, mcn);
    (void)hipMemsetAsync((char*)d_out + O_MAXSM * 4, 0, 2 * sizeof(float), stream);
    k_epi<<<dim3((Bb * Nn) / 4), 256, 0, stream>>>(part, zp, pp, out, mcn);
}

// Round 14
// 285.851 us; speedup vs baseline: 1.1731x; 1.1731x over previous
//
#include <hip/hip_runtime.h>
#include <hip/hip_bf16.h>

// ---------------- problem constants ----------------
#define Bb   2
#define Cc   256
#define Nn   1024
#define Mm   65536
#define VROWS 272         // 256 desc + 3 coords + 1 weight + ones + 11 pad
#define MSTEP 32

// workspace byte offsets (fixed part)
#define SCL_OFF  0L                               // B*M f32           (0.5 MB)
#define TMC_OFF  524288L                          // B*M*C bf16        (67 MB)   K: [b][m][c]
#define TCM_OFF  67633152L                        // B*272*M bf16      (71.3 MB) V: [b][row][m]
#define SNC_OFF  138936320L                       // B*N*C bf16        (1 MB)    Q^T: [b][n][c]
#define PART_OFF 139984896L                       // B*mcn*N*272 bf16  (runtime mcn)
// stats partials live in the part region (consumed before k_main writes part)
#define PS_OFF   PART_OFF                         // [B][4][M] f32 sums   (2 MB)
#define PS2_OFF  (PART_OFF + 2097152L)            // [B][4][M] f32 sumsq  (2 MB)

// output float offsets
#define O_COORD 0L
#define O_W     6144L
#define O_DESC  8192L
#define O_P2D   532480L
#define O_VALID 536576L
#define O_MAXSM 538624L

using f32x4 = __attribute__((ext_vector_type(4))) float;
using s16x8 = __attribute__((ext_vector_type(8))) short;

__device__ inline unsigned short f2bf(float x) {
    union { float f; unsigned int u; } v; v.f = x;
    unsigned int r = v.u + 0x7FFFu + ((v.u >> 16) & 1u);   // RNE
    return (unsigned short)(r >> 16);
}
__device__ inline float bf2f(unsigned short u) {
    union { unsigned int u; float f; } v; v.u = ((unsigned int)u) << 16;
    return v.f;
}
__device__ inline float exp2v(float x) {
    float r; asm("v_exp_f32 %0, %1" : "=v"(r) : "v"(x)); return r;
}
__device__ inline unsigned int cvtpk(float lo, float hi) {
    unsigned int r;
    asm("v_cvt_pk_bf16_f32 %0, %1, %2" : "=v"(r) : "v"(lo), "v"(hi));
    return r;
}

__device__ inline void gld_lds16(const unsigned short* g, unsigned short* l) {
    __builtin_amdgcn_global_load_lds(
        (const __attribute__((address_space(1))) unsigned int*)g,
        (__attribute__((address_space(3))) unsigned int*)l, 16, 0, 0);
}

// ------- prep A: tgt_desc f32 -> tmc bf16 [b][m][c] + tcm bf16 [b][c][m],
//                 plus per-(c-block, m) partial sums for the column stats -------
__global__ void k_prep_tgt(const float* __restrict__ tgt,
                           unsigned short* __restrict__ tmc,
                           unsigned short* __restrict__ tcm,
                           float* __restrict__ ps,
                           float* __restrict__ ps2) {
    __shared__ float lds[64][65];
    __shared__ float sm[4][64], sm2[4][64];
    int b = blockIdx.z, cy = blockIdx.y, c0 = cy * 64;
    long m0 = (long)blockIdx.x * 64;
    int ty = threadIdx.x >> 6, tx = threadIdx.x & 63;
    float s = 0.f, s2 = 0.f;
    #pragma unroll
    for (int k = 0; k < 16; ++k) {
        int ci = 4 * k + ty;
        float v = tgt[((long)b * Cc + c0 + ci) * Mm + m0 + tx];
        lds[ci][tx] = v;
        s += v; s2 += v * v;
        tcm[((long)b * VROWS + c0 + ci) * Mm + m0 + tx] = f2bf(v);
    }
    sm[ty][tx] = s; sm2[ty][tx] = s2;
    __syncthreads();
    #pragma unroll
    for (int k = 0; k < 16; ++k) {
        int mi = 4 * k + ty;
        tmc[((long)b * Mm + m0 + mi) * Cc + c0 + tx] = f2bf(lds[tx][mi]);
    }
    if (ty == 0) {
        long o = ((long)b * 4 + cy) * Mm + m0 + tx;
        ps[o]  = (sm[0][tx] + sm[1][tx]) + (sm[2][tx] + sm[3][tx]);
        ps2[o] = (sm2[0][tx] + sm2[1][tx]) + (sm2[2][tx] + sm2[3][tx]);
    }
}

// ------- prep B: finish stats -> scl; write coords/weights/ones rows of V -------
__global__ void k_stats(const float* __restrict__ ps,
                        const float* __restrict__ ps2,
                        const float* __restrict__ coords,
                        const float* __restrict__ weights,
                        float* __restrict__ scl,
                        unsigned short* __restrict__ tcm) {
    int b = blockIdx.y;
    long m = (long)blockIdx.x * 256 + threadIdx.x;
    float s = 0.f, s2 = 0.f;
    #pragma unroll
    for (int k = 0; k < 4; ++k) {
        long o = ((long)b * 4 + k) * Mm + m;
        s += ps[o]; s2 += ps2[o];
    }
    float var = fmaxf((s2 - s * s * (1.0f / Cc)) * (1.0f / (Cc - 1)), 1e-20f);
    scl[(long)b * Mm + m] = 1.4426950408889634f * rsqrtf(var) * (1.0f / (Cc * 0.01f));
    unsigned short* vrow = tcm + ((long)b * VROWS + 256) * Mm + m;
    #pragma unroll
    for (int i = 0; i < 3; ++i) vrow[(long)i * Mm] = f2bf(coords[((long)b * 3 + i) * Mm + m]);
    vrow[3L * Mm] = f2bf(weights[(long)b * Mm + m]);
    vrow[4L * Mm] = 0x3F80;   // ones row (channel 260): Z comes out of the PV MFMA
    #pragma unroll
    for (int i = 5; i < 16; ++i) vrow[(long)i * Mm] = 0;
}

// ------- prep C: src_desc_norm f32 -> snc bf16 [b][n][c] -------
__global__ void k_prep_src(const float* __restrict__ src, unsigned short* __restrict__ snc) {
    __shared__ float lds[64][65];
    int b = blockIdx.z, c0 = blockIdx.y * 64, n0 = blockIdx.x * 64;
    int ty = threadIdx.x >> 6, tx = threadIdx.x & 63;
    #pragma unroll
    for (int k = 0; k < 16; ++k)
        lds[4 * k + ty][tx] = src[((long)b * Cc + c0 + 4 * k + ty) * Nn + n0 + tx];
    __syncthreads();
    #pragma unroll
    for (int k = 0; k < 16; ++k) {
        int ni = 4 * k + ty;
        snc[((long)b * Nn + n0 + ni) * Cc + c0 + tx] = f2bf(lds[tx][ni]);
    }
}

// ------- main fused kernel: 32 n per wave, 2 blocks per CU -------
// 4 waves * 32 n = 128 n per block; LDS squeezed to 76 KB so TWO independent
// blocks co-reside per CU (2 waves/SIMD, no shared barrier -> phases drift and
// cover each other's stalls). K/V double-buffered, pbuf wave-private single.
__global__ __launch_bounds__(256, 2) void k_main(const unsigned short* __restrict__ tmc,
                                                 const unsigned short* __restrict__ tcm,
                                                 const unsigned short* __restrict__ snc,
                                                 const float* __restrict__ scl,
                                                 unsigned short* __restrict__ part,
                                                 float* __restrict__ zp,
                                                 float* __restrict__ pp,
                                                 int mcn) {
    __shared__ __align__(16) unsigned short kb[2][8192];          // 32 KB
    __shared__ __align__(16) unsigned short vb[2][8704];          // 34 KB
    __shared__ __align__(16) unsigned short pbuf[4][2][16][40];   // 10 KB   total 76 KB

    int w = threadIdx.x >> 6, lane = threadIdx.x & 63;
    int l15 = lane & 15, lg = lane >> 4;
    int b = blockIdx.z, nt = blockIdx.y, mc = blockIdx.x;
    int nb = nt * 128 + w * 32;
    int mchunk = Mm / mcn;
    int nit = mchunk / MSTEP;
    long mbase = (long)mc * mchunk;

    // Q^T B-fragments for 2 n-subtiles (64 VGPR)
    s16x8 qf[2][8];
    #pragma unroll
    for (int st = 0; st < 2; ++st) {
        const unsigned short* qp = snc + ((long)b * Nn + nb + st * 16 + l15) * Cc + lg * 8;
        #pragma unroll
        for (int cc = 0; cc < 8; ++cc) qf[st][cc] = *(const s16x8*)(qp + cc * 32);
    }

    f32x4 acc[2][17];
    #pragma unroll
    for (int st = 0; st < 2; ++st)
        #pragma unroll
        for (int t = 0; t < 17; ++t) acc[st][t] = (f32x4){0.f, 0.f, 0.f, 0.f};
    float pmax[2] = {0.f, 0.f};

    // ---- staging: uniform bases (SGPR) + u32 element offsets (VGPR) ----
    const unsigned short* tmcb = tmc + (long)b * Mm * Cc;
    const unsigned short* tcmb = tcm + (long)b * VROWS * (long)Mm;
    unsigned koff[4];
    #pragma unroll
    for (int i = 0; i < 4; ++i) {
        int ins = w * 4 + i;                 // K instr 0..15, covers rows 2*ins, 2*ins+1
        int row = 2 * ins + (lane >> 5);
        int gs  = (lane & 31) ^ (row & 7);   // pre-swizzled 16B slot
        koff[i] = (unsigned)((mbase + row) * Cc + gs * 8);
    }
    unsigned voff[5];
    int vj = ((lane & 3) ^ ((lane >> 3) & 3)) * 8;   // chunk-XOR pre-swizzle
    #pragma unroll
    for (int i = 0; i < 5; ++i) {
        int ins = (i < 4) ? (w * 4 + i) : 16;
        int row = ins * 16 + (lane >> 2);
        voff[i] = (unsigned)((long)row * Mm + mbase + vj);
    }

    const float* sclb = scl + (long)b * Mm;

    auto stage = [&](int d) {
        unsigned short* kd = kb[d];
        unsigned short* vd = vb[d];
        #pragma unroll
        for (int i = 0; i < 4; ++i) gld_lds16(tmcb + koff[i], kd + (w * 4 + i) * 512);
        #pragma unroll
        for (int i = 0; i < 4; ++i) gld_lds16(tcmb + voff[i], vd + (w * 4 + i) * 512);
        if (w == 3) gld_lds16(tcmb + voff[4], vd + 16 * 512);
        #pragma unroll
        for (int i = 0; i < 4; ++i) koff[i] += MSTEP * Cc;
        #pragma unroll
        for (int i = 0; i < 5; ++i) voff[i] += MSTEP;
    };

    int ksw = (l15 & 7) << 3;              // K read swizzle (elements)
    int vsw = (lg ^ ((l15 >> 1) & 3)) * 8; // V read chunk swizzle (elements)

    stage(0);
    __syncthreads();

    for (int s = 0; s < nit; ++s) {
        int cur = s & 1;
        if (s + 1 < nit) stage(cur ^ 1);
        const unsigned short* kbc = kb[cur];
        const unsigned short* vbc = vb[cur];
        long m0 = mbase + (long)s * MSTEP;
        float4 sc0 = *(const float4*)(sclb + m0 + lg * 4);
        float4 sc1 = *(const float4*)(sclb + m0 + 16 + lg * 4);

        // ---- QK: 2 m-subtiles x 2 n-subtiles ----
        #pragma unroll
        for (int t = 0; t < 2; ++t) {
            f32x4 dA = (f32x4){0.f, 0.f, 0.f, 0.f};
            f32x4 dB = (f32x4){0.f, 0.f, 0.f, 0.f};
            const unsigned short* kr = kbc + (t * 16 + l15) * Cc;
            #pragma unroll
            for (int cc = 0; cc < 8; ++cc) {
                s16x8 kf = *(const s16x8*)(kr + ((cc * 32 + lg * 8) ^ ksw));
                dA = __builtin_amdgcn_mfma_f32_16x16x32_bf16(kf, qf[0][cc], dA, 0, 0, 0);
                dB = __builtin_amdgcn_mfma_f32_16x16x32_bf16(kf, qf[1][cc], dB, 0, 0, 0);
            }
            float4 sc = t ? sc1 : sc0;
            #pragma unroll
            for (int st = 0; st < 2; ++st) {
                f32x4 d = st ? dB : dA;
                float p0 = exp2v(d.x * sc.x);
                float p1 = exp2v(d.y * sc.y);
                float p2 = exp2v(d.z * sc.z);
                float p3 = exp2v(d.w * sc.w);
                pmax[st] = fmaxf(pmax[st], fmaxf(fmaxf(p0, p1), fmaxf(p2, p3)));
                unsigned long long pk =
                    (unsigned long long)cvtpk(p0, p1) | ((unsigned long long)cvtpk(p2, p3) << 32);
                *(unsigned long long*)&pbuf[w][st][l15][t * 16 + lg * 4] = pk;
            }
        }
        // ---- PV: 17 output c-tiles; V-frag shared across both n-subtiles ----
        s16x8 pfA = *(const s16x8*)&pbuf[w][0][l15][lg * 8];
        s16x8 pfB = *(const s16x8*)&pbuf[w][1][l15][lg * 8];
        #pragma unroll
        for (int t = 0; t < 17; ++t) {
            s16x8 vf = *(const s16x8*)(vbc + (t * 16 + l15) * MSTEP + vsw);
            acc[0][t] = __builtin_amdgcn_mfma_f32_16x16x32_bf16(vf, pfA, acc[0][t], 0, 0, 0);
            acc[1][t] = __builtin_amdgcn_mfma_f32_16x16x32_bf16(vf, pfB, acc[1][t], 0, 0, 0);
        }
        __syncthreads();
    }

    // Z sits in acc[st][16].x on lanes lg==1 (channel 260 = ones row)
    #pragma unroll
    for (int st = 0; st < 2; ++st) {
        float pt = fmaxf(pmax[st], __shfl_xor(pmax[st], 16));
        pt = fmaxf(pt, __shfl_xor(pt, 32));
        long zi = ((long)(b * mcn + mc)) * Nn + nb + st * 16;
        if (lg == 1) zp[zi + l15] = acc[st][16].x;
        if (lane < 16) pp[zi + lane] = pt;
        unsigned short* po = part + (((long)(b * mcn + mc) * Nn) + nb + st * 16 + l15) * VROWS;
        #pragma unroll
        for (int t = 0; t < 17; ++t) {
            f32x4 a = acc[st][t];
            unsigned long long pk =
                (unsigned long long)cvtpk(a.x, a.y) | ((unsigned long long)cvtpk(a.z, a.w) << 32);
            *(unsigned long long*)&po[t * 16 + lg * 4] = pk;
        }
    }
}

// ------- epilogue: combine m-chunks, normalize, zn(descs), 2D projection, max_softmax -------
__global__ void k_epi(const unsigned short* __restrict__ part,
                      const float* __restrict__ zp,
                      const float* __restrict__ pp,
                      float* __restrict__ out,
                      int mcn) {
    int w = threadIdx.x >> 6, lane = threadIdx.x & 63;
    int bn = blockIdx.x * 4 + w;
    int b = bn >> 10, n = bn & 1023;

    float Z = 0.f, pm = 0.f;
    for (int mc = 0; mc < mcn; ++mc) {
        long zi = ((long)(b * mcn + mc)) * Nn + n;
        Z += zp[zi];
        pm = fmaxf(pm, pp[zi]);
    }
    float invZ = 1.0f / Z;

    float dv[4], s1 = 0.f, s2 = 0.f;
    #pragma unroll
    for (int k = 0; k < 4; ++k) {
        int c = lane + 64 * k;
        float s = 0.f;
        for (int mc = 0; mc < mcn; ++mc)
            s += bf2f(part[((long)(b * mcn + mc) * Nn + n) * VROWS + c]);
        float d = s * invZ;
        dv[k] = d; s1 += d; s2 += d * d;
    }
    #pragma unroll
    for (int off = 1; off < 64; off <<= 1) { s1 += __shfl_xor(s1, off); s2 += __shfl_xor(s2, off); }
    float mean = s1 * (1.0f / 256.0f);
    float var = fmaxf((s2 - 256.0f * mean * mean) * (1.0f / 255.0f), 1e-20f);
    float istd = 1.0f / sqrtf(var);
    #pragma unroll
    for (int k = 0; k < 4; ++k)
        out[O_DESC + ((long)b * Cc + lane + 64 * k) * Nn + n] = (dv[k] - mean) * istd;

    float ex = 0.f;
    if (lane < 4) {
        int c = 256 + lane;
        for (int mc = 0; mc < mcn; ++mc)
            ex += bf2f(part[((long)(b * mcn + mc) * Nn + n) * VROWS + c]);
        ex *= invZ;
    }
    float pc0 = __shfl(ex, 0), pc1 = __shfl(ex, 1), pc2 = __shfl(ex, 2), wv = __shfl(ex, 3);
    if (lane == 0) {
        out[O_COORD + ((long)b * 3 + 0) * Nn + n] = pc0;
        out[O_COORD + ((long)b * 3 + 1) * Nn + n] = pc1;
        out[O_COORD + ((long)b * 3 + 2) * Nn + n] = pc2;
        out[O_W + (long)b * Nn + n] = wv;
        const float cmin = 33.048f;                 // (256/2 - 0.5) * 0.2592
        out[O_P2D + ((long)b * Nn + n) * 2 + 0] = (cmin + pc1) * (1.0f / 0.2592f);
        out[O_P2D + ((long)b * Nn + n) * 2 + 1] = (cmin - pc0) * (1.0f / 0.2592f);
        out[O_VALID + (long)b * Nn + n] = 1.0f;
        atomicMax((unsigned int*)out + O_MAXSM + b, __float_as_uint(pm * invZ));
    }
}

extern "C" void kernel_launch(void* const* d_in, const int* in_sizes, int n_in,
                              void* d_out, int out_size, void* d_ws, size_t ws_size,
                              hipStream_t stream) {
    const float* tgt_coords  = (const float*)d_in[1];
    const float* tgt_weights = (const float*)d_in[3];
    const float* src_desc    = (const float*)d_in[5];
    const float* tgt_desc    = (const float*)d_in[6];

    char* ws = (char*)d_ws;
    float* scl           = (float*)(ws + SCL_OFF);
    unsigned short* tmc  = (unsigned short*)(ws + TMC_OFF);
    unsigned short* tcm  = (unsigned short*)(ws + TCM_OFF);
    unsigned short* snc  = (unsigned short*)(ws + SNC_OFF);
    unsigned short* part = (unsigned short*)(ws + PART_OFF);
    float* ps            = (float*)(ws + PS_OFF);
    float* ps2           = (float*)(ws + PS2_OFF);
    float* out           = (float*)d_out;

    // choose m-chunk count by available workspace: 32 chunks needs ~176 MB
    long need32 = PART_OFF + (long)Bb * 32 * Nn * VROWS * 2 + 2L * Bb * 32 * Nn * 4;
    int mcn = (ws_size >= (size_t)need32) ? 32 : 16;
    long zp_off = PART_OFF + (long)Bb * mcn * Nn * VROWS * 2;
    long pp_off = zp_off + (long)Bb * mcn * Nn * 4;
    float* zp = (float*)(ws + zp_off);
    float* pp = (float*)(ws + pp_off);

    k_prep_tgt<<<dim3(Mm / 64, Cc / 64, Bb), 256, 0, stream>>>(tgt_desc, tmc, tcm, ps, ps2);
    k_stats<<<dim3(Mm / 256, Bb), 256, 0, stream>>>(ps, ps2, tgt_coords, tgt_weights, scl, tcm);
    k_prep_src<<<dim3(Nn / 64, Cc / 64, Bb), 256, 0, stream>>>(src_desc, snc);
    k_main<<<dim3(mcn, Nn / 128, Bb), 256, 0, stream>>>(tmc, tcm, snc, scl, part, zp, pp, mcn);
    (void)hipMemsetAsync((char*)d_out + O_MAXSM * 4, 0, 2 * sizeof(float), stream);
    k_epi<<<dim3((Bb * Nn) / 4), 256, 0, stream>>>(part, zp, pp, out, mcn);
}

// Round 15
// 279.204 us; speedup vs baseline: 1.2010x; 1.0238x over previous
//
#include <hip/hip_runtime.h>
#include <hip/hip_bf16.h>

// ---------------- problem constants ----------------
#define Bb   2
#define Cc   256
#define Nn   1024
#define Mm   65536
#define VROWS 272         // 256 desc + 3 coords + 1 weight + ones + 11 pad
#define MSTEP 32

// workspace byte offsets (fixed part)
#define SCL_OFF  0L                               // B*M f32           (0.5 MB)
#define TMC_OFF  524288L                          // B*M*C bf16        (67 MB)   K: [b][m][c]
#define TCM_OFF  67633152L                        // B*272*M bf16      (71.3 MB) V: [b][row][m]
#define SNC_OFF  138936320L                       // B*N*C bf16        (1 MB)    Q^T: [b][n][c]
#define PART_OFF 139984896L                       // B*mcn*N*272 bf16  (runtime mcn)
// stats partials live in the part region (consumed before k_main writes part)
#define PS_OFF   PART_OFF                         // [B][4][M] f32 sums   (2 MB)
#define PS2_OFF  (PART_OFF + 2097152L)            // [B][4][M] f32 sumsq  (2 MB)

// output float offsets
#define O_COORD 0L
#define O_W     6144L
#define O_DESC  8192L
#define O_P2D   532480L
#define O_VALID 536576L
#define O_MAXSM 538624L

using f32x4 = __attribute__((ext_vector_type(4))) float;
using s16x8 = __attribute__((ext_vector_type(8))) short;

__device__ inline unsigned short f2bf(float x) {
    union { float f; unsigned int u; } v; v.f = x;
    unsigned int r = v.u + 0x7FFFu + ((v.u >> 16) & 1u);   // RNE
    return (unsigned short)(r >> 16);
}
__device__ inline float bf2f(unsigned short u) {
    union { unsigned int u; float f; } v; v.u = ((unsigned int)u) << 16;
    return v.f;
}
__device__ inline float exp2v(float x) {
    float r; asm("v_exp_f32 %0, %1" : "=v"(r) : "v"(x)); return r;
}
__device__ inline unsigned int cvtpk(float lo, float hi) {
    unsigned int r;
    asm("v_cvt_pk_bf16_f32 %0, %1, %2" : "=v"(r) : "v"(lo), "v"(hi));
    return r;
}

__device__ inline void gld_lds16(const unsigned short* g, unsigned short* l) {
    __builtin_amdgcn_global_load_lds(
        (const __attribute__((address_space(1))) unsigned int*)g,
        (__attribute__((address_space(3))) unsigned int*)l, 16, 0, 0);
}

// ------- prep A: tgt_desc f32 -> tmc bf16 [b][m][c] + tcm bf16 [b][c][m],
//                 plus per-(c-block, m) partial sums for the column stats -------
__global__ void k_prep_tgt(const float* __restrict__ tgt,
                           unsigned short* __restrict__ tmc,
                           unsigned short* __restrict__ tcm,
                           float* __restrict__ ps,
                           float* __restrict__ ps2) {
    __shared__ float lds[64][65];
    __shared__ float sm[4][64], sm2[4][64];
    int b = blockIdx.z, cy = blockIdx.y, c0 = cy * 64;
    long m0 = (long)blockIdx.x * 64;
    int ty = threadIdx.x >> 6, tx = threadIdx.x & 63;
    float s = 0.f, s2 = 0.f;
    #pragma unroll
    for (int k = 0; k < 16; ++k) {
        int ci = 4 * k + ty;
        float v = tgt[((long)b * Cc + c0 + ci) * Mm + m0 + tx];
        lds[ci][tx] = v;
        s += v; s2 += v * v;
        tcm[((long)b * VROWS + c0 + ci) * Mm + m0 + tx] = f2bf(v);
    }
    sm[ty][tx] = s; sm2[ty][tx] = s2;
    __syncthreads();
    #pragma unroll
    for (int k = 0; k < 16; ++k) {
        int mi = 4 * k + ty;
        tmc[((long)b * Mm + m0 + mi) * Cc + c0 + tx] = f2bf(lds[tx][mi]);
    }
    if (ty == 0) {
        long o = ((long)b * 4 + cy) * Mm + m0 + tx;
        ps[o]  = (sm[0][tx] + sm[1][tx]) + (sm[2][tx] + sm[3][tx]);
        ps2[o] = (sm2[0][tx] + sm2[1][tx]) + (sm2[2][tx] + sm2[3][tx]);
    }
}

// ------- prep B: finish stats -> scl; write coords/weights/ones rows of V -------
__global__ void k_stats(const float* __restrict__ ps,
                        const float* __restrict__ ps2,
                        const float* __restrict__ coords,
                        const float* __restrict__ weights,
                        float* __restrict__ scl,
                        unsigned short* __restrict__ tcm) {
    int b = blockIdx.y;
    long m = (long)blockIdx.x * 256 + threadIdx.x;
    float s = 0.f, s2 = 0.f;
    #pragma unroll
    for (int k = 0; k < 4; ++k) {
        long o = ((long)b * 4 + k) * Mm + m;
        s += ps[o]; s2 += ps2[o];
    }
    float var = fmaxf((s2 - s * s * (1.0f / Cc)) * (1.0f / (Cc - 1)), 1e-20f);
    scl[(long)b * Mm + m] = 1.4426950408889634f * rsqrtf(var) * (1.0f / (Cc * 0.01f));
    unsigned short* vrow = tcm + ((long)b * VROWS + 256) * Mm + m;
    #pragma unroll
    for (int i = 0; i < 3; ++i) vrow[(long)i * Mm] = f2bf(coords[((long)b * 3 + i) * Mm + m]);
    vrow[3L * Mm] = f2bf(weights[(long)b * Mm + m]);
    vrow[4L * Mm] = 0x3F80;   // ones row (channel 260): Z comes out of the PV MFMA
    #pragma unroll
    for (int i = 5; i < 16; ++i) vrow[(long)i * Mm] = 0;
}

// ------- prep C: src_desc_norm f32 -> snc bf16 [b][n][c] -------
__global__ void k_prep_src(const float* __restrict__ src, unsigned short* __restrict__ snc) {
    __shared__ float lds[64][65];
    int b = blockIdx.z, c0 = blockIdx.y * 64, n0 = blockIdx.x * 64;
    int ty = threadIdx.x >> 6, tx = threadIdx.x & 63;
    #pragma unroll
    for (int k = 0; k < 16; ++k)
        lds[4 * k + ty][tx] = src[((long)b * Cc + c0 + 4 * k + ty) * Nn + n0 + tx];
    __syncthreads();
    #pragma unroll
    for (int k = 0; k < 16; ++k) {
        int ni = 4 * k + ty;
        snc[((long)b * Nn + n0 + ni) * Cc + c0 + tx] = f2bf(lds[tx][ni]);
    }
}

// ------- main fused kernel: 32 n per wave, 2 blocks per CU, reg-only P -------
// K rows within each 32-m tile are stored PERMUTED in LDS:
//   LDS row a  holds global K row  perm(a) = ((a>>2)&3)*8 + (a>>4)*4 + (a&3)
// so the QK D-fragment (lane: m = lg*4+r per 16-subtile t) directly yields the
// PV B-fragment (lane: m_phys = lg*8 + t*4 + r) after lane-local cvt_pk packing.
// No P LDS round-trip, no lgkm wait; V stays in natural m order.
__global__ __launch_bounds__(256, 2) void k_main(const unsigned short* __restrict__ tmc,
                                                 const unsigned short* __restrict__ tcm,
                                                 const unsigned short* __restrict__ snc,
                                                 const float* __restrict__ scl,
                                                 unsigned short* __restrict__ part,
                                                 float* __restrict__ zp,
                                                 float* __restrict__ pp,
                                                 int mcn) {
    __shared__ __align__(16) unsigned short kb[2][8192];          // 32 KB
    __shared__ __align__(16) unsigned short vb[2][8704];          // 34 KB  total 66 KB

    int w = threadIdx.x >> 6, lane = threadIdx.x & 63;
    int l15 = lane & 15, lg = lane >> 4;
    int b = blockIdx.z, nt = blockIdx.y, mc = blockIdx.x;
    int nb = nt * 128 + w * 32;
    int mchunk = Mm / mcn;
    int nit = mchunk / MSTEP;
    long mbase = (long)mc * mchunk;

    // Q^T B-fragments for 2 n-subtiles (64 VGPR)
    s16x8 qf[2][8];
    #pragma unroll
    for (int st = 0; st < 2; ++st) {
        const unsigned short* qp = snc + ((long)b * Nn + nb + st * 16 + l15) * Cc + lg * 8;
        #pragma unroll
        for (int cc = 0; cc < 8; ++cc) qf[st][cc] = *(const s16x8*)(qp + cc * 32);
    }

    f32x4 acc[2][17];
    #pragma unroll
    for (int st = 0; st < 2; ++st)
        #pragma unroll
        for (int t = 0; t < 17; ++t) acc[st][t] = (f32x4){0.f, 0.f, 0.f, 0.f};
    float pmax[2] = {0.f, 0.f};

    // ---- staging: uniform bases (SGPR) + u32 element offsets (VGPR) ----
    const unsigned short* tmcb = tmc + (long)b * Mm * Cc;
    const unsigned short* tcmb = tcm + (long)b * VROWS * (long)Mm;
    unsigned koff[4];
    #pragma unroll
    for (int i = 0; i < 4; ++i) {
        int ins = w * 4 + i;                  // K instr 0..15, covers LDS rows 2*ins, 2*ins+1
        int a   = 2 * ins + (lane >> 5);      // LDS row
        int pa  = ((a >> 2) & 3) * 8 + ((a >> 4) << 2) + (a & 3);   // source global row
        int gs  = (lane & 31) ^ (a & 7);      // pre-swizzled 16B slot (keyed to LDS row)
        koff[i] = (unsigned)((mbase + pa) * Cc + gs * 8);
    }
    unsigned voff[5];
    int vj = ((lane & 3) ^ ((lane >> 3) & 3)) * 8;   // chunk-XOR pre-swizzle
    #pragma unroll
    for (int i = 0; i < 5; ++i) {
        int ins = (i < 4) ? (w * 4 + i) : 16;
        int row = ins * 16 + (lane >> 2);
        voff[i] = (unsigned)((long)row * Mm + mbase + vj);
    }

    const float* sclb = scl + (long)b * Mm;

    auto stage = [&](int d) {
        unsigned short* kd = kb[d];
        unsigned short* vd = vb[d];
        #pragma unroll
        for (int i = 0; i < 4; ++i) gld_lds16(tmcb + koff[i], kd + (w * 4 + i) * 512);
        #pragma unroll
        for (int i = 0; i < 4; ++i) gld_lds16(tcmb + voff[i], vd + (w * 4 + i) * 512);
        if (w == 3) gld_lds16(tcmb + voff[4], vd + 16 * 512);
        #pragma unroll
        for (int i = 0; i < 4; ++i) koff[i] += MSTEP * Cc;
        #pragma unroll
        for (int i = 0; i < 5; ++i) voff[i] += MSTEP;
    };

    int ksw = (l15 & 7) << 3;              // K read swizzle (elements)
    int vsw = (lg ^ ((l15 >> 1) & 3)) * 8; // V read chunk swizzle (elements)

    stage(0);
    __syncthreads();

    for (int s = 0; s < nit; ++s) {
        int cur = s & 1;
        if (s + 1 < nit) stage(cur ^ 1);
        const unsigned short* kbc = kb[cur];
        const unsigned short* vbc = vb[cur];
        long m0 = mbase + (long)s * MSTEP;
        // scl for D position (t,lg,r) = physical m = lg*8 + t*4 + r
        float4 sc0 = *(const float4*)(sclb + m0 + lg * 8);       // t=0
        float4 sc1 = *(const float4*)(sclb + m0 + lg * 8 + 4);   // t=1

        // ---- QK: 2 m-subtiles x 2 n-subtiles; P packed in registers ----
        unsigned int pwA[4], pwB[4];
        #pragma unroll
        for (int t = 0; t < 2; ++t) {
            f32x4 dA = (f32x4){0.f, 0.f, 0.f, 0.f};
            f32x4 dB = (f32x4){0.f, 0.f, 0.f, 0.f};
            const unsigned short* kr = kbc + (t * 16 + l15) * Cc;
            #pragma unroll
            for (int cc = 0; cc < 8; ++cc) {
                s16x8 kf = *(const s16x8*)(kr + ((cc * 32 + lg * 8) ^ ksw));
                dA = __builtin_amdgcn_mfma_f32_16x16x32_bf16(kf, qf[0][cc], dA, 0, 0, 0);
                dB = __builtin_amdgcn_mfma_f32_16x16x32_bf16(kf, qf[1][cc], dB, 0, 0, 0);
            }
            float4 sc = t ? sc1 : sc0;
            {
                float p0 = exp2v(dA.x * sc.x);
                float p1 = exp2v(dA.y * sc.y);
                float p2 = exp2v(dA.z * sc.z);
                float p3 = exp2v(dA.w * sc.w);
                pmax[0] = fmaxf(pmax[0], fmaxf(fmaxf(p0, p1), fmaxf(p2, p3)));
                pwA[t * 2 + 0] = cvtpk(p0, p1);
                pwA[t * 2 + 1] = cvtpk(p2, p3);
            }
            {
                float p0 = exp2v(dB.x * sc.x);
                float p1 = exp2v(dB.y * sc.y);
                float p2 = exp2v(dB.z * sc.z);
                float p3 = exp2v(dB.w * sc.w);
                pmax[1] = fmaxf(pmax[1], fmaxf(fmaxf(p0, p1), fmaxf(p2, p3)));
                pwB[t * 2 + 0] = cvtpk(p0, p1);
                pwB[t * 2 + 1] = cvtpk(p2, p3);
            }
        }
        union PU { unsigned int u[4]; s16x8 f; };
        PU puA, puB;
        #pragma unroll
        for (int j = 0; j < 4; ++j) { puA.u[j] = pwA[j]; puB.u[j] = pwB[j]; }
        s16x8 pfA = puA.f;
        s16x8 pfB = puB.f;

        // ---- PV: 17 output c-tiles; V-frag shared across both n-subtiles ----
        #pragma unroll
        for (int t = 0; t < 17; ++t) {
            s16x8 vf = *(const s16x8*)(vbc + (t * 16 + l15) * MSTEP + vsw);
            acc[0][t] = __builtin_amdgcn_mfma_f32_16x16x32_bf16(vf, pfA, acc[0][t], 0, 0, 0);
            acc[1][t] = __builtin_amdgcn_mfma_f32_16x16x32_bf16(vf, pfB, acc[1][t], 0, 0, 0);
        }
        __syncthreads();
    }

    // Z sits in acc[st][16].x on lanes lg==1 (channel 260 = ones row)
    #pragma unroll
    for (int st = 0; st < 2; ++st) {
        float pt = fmaxf(pmax[st], __shfl_xor(pmax[st], 16));
        pt = fmaxf(pt, __shfl_xor(pt, 32));
        long zi = ((long)(b * mcn + mc)) * Nn + nb + st * 16;
        if (lg == 1) zp[zi + l15] = acc[st][16].x;
        if (lane < 16) pp[zi + lane] = pt;
        unsigned short* po = part + (((long)(b * mcn + mc) * Nn) + nb + st * 16 + l15) * VROWS;
        #pragma unroll
        for (int t = 0; t < 17; ++t) {
            f32x4 a = acc[st][t];
            unsigned long long pk =
                (unsigned long long)cvtpk(a.x, a.y) | ((unsigned long long)cvtpk(a.z, a.w) << 32);
            *(unsigned long long*)&po[t * 16 + lg * 4] = pk;
        }
    }
}

// ------- epilogue: combine m-chunks, normalize, zn(descs), 2D projection, max_softmax -------
__global__ void k_epi(const unsigned short* __restrict__ part,
                      const float* __restrict__ zp,
                      const float* __restrict__ pp,
                      float* __restrict__ out,
                      int mcn) {
    int w = threadIdx.x >> 6, lane = threadIdx.x & 63;
    int bn = blockIdx.x * 4 + w;
    int b = bn >> 10, n = bn & 1023;

    float Z = 0.f, pm = 0.f;
    for (int mc = 0; mc < mcn; ++mc) {
        long zi = ((long)(b * mcn + mc)) * Nn + n;
        Z += zp[zi];
        pm = fmaxf(pm, pp[zi]);
    }
    float invZ = 1.0f / Z;

    float dv[4], s1 = 0.f, s2 = 0.f;
    #pragma unroll
    for (int k = 0; k < 4; ++k) {
        int c = lane + 64 * k;
        float s = 0.f;
        for (int mc = 0; mc < mcn; ++mc)
            s += bf2f(part[((long)(b * mcn + mc) * Nn + n) * VROWS + c]);
        float d = s * invZ;
        dv[k] = d; s1 += d; s2 += d * d;
    }
    #pragma unroll
    for (int off = 1; off < 64; off <<= 1) { s1 += __shfl_xor(s1, off); s2 += __shfl_xor(s2, off); }
    float mean = s1 * (1.0f / 256.0f);
    float var = fmaxf((s2 - 256.0f * mean * mean) * (1.0f / 255.0f), 1e-20f);
    float istd = 1.0f / sqrtf(var);
    #pragma unroll
    for (int k = 0; k < 4; ++k)
        out[O_DESC + ((long)b * Cc + lane + 64 * k) * Nn + n] = (dv[k] - mean) * istd;

    float ex = 0.f;
    if (lane < 4) {
        int c = 256 + lane;
        for (int mc = 0; mc < mcn; ++mc)
            ex += bf2f(part[((long)(b * mcn + mc) * Nn + n) * VROWS + c]);
        ex *= invZ;
    }
    float pc0 = __shfl(ex, 0), pc1 = __shfl(ex, 1), pc2 = __shfl(ex, 2), wv = __shfl(ex, 3);
    if (lane == 0) {
        out[O_COORD + ((long)b * 3 + 0) * Nn + n] = pc0;
        out[O_COORD + ((long)b * 3 + 1) * Nn + n] = pc1;
        out[O_COORD + ((long)b * 3 + 2) * Nn + n] = pc2;
        out[O_W + (long)b * Nn + n] = wv;
        const float cmin = 33.048f;                 // (256/2 - 0.5) * 0.2592
        out[O_P2D + ((long)b * Nn + n) * 2 + 0] = (cmin + pc1) * (1.0f / 0.2592f);
        out[O_P2D + ((long)b * Nn + n) * 2 + 1] = (cmin - pc0) * (1.0f / 0.2592f);
        out[O_VALID + (long)b * Nn + n] = 1.0f;
        atomicMax((unsigned int*)out + O_MAXSM + b, __float_as_uint(pm * invZ));
    }
}

extern "C" void kernel_launch(void* const* d_in, const int* in_sizes, int n_in,
                              void* d_out, int out_size, void* d_ws, size_t ws_size,
                              hipStream_t stream) {
    const float* tgt_coords  = (const float*)d_in[1];
    const float* tgt_weights = (const float*)d_in[3];
    const float* src_desc    = (const float*)d_in[5];
    const float* tgt_desc    = (const float*)d_in[6];

    char* ws = (char*)d_ws;
    float* scl           = (float*)(ws + SCL_OFF);
    unsigned short* tmc  = (unsigned short*)(ws + TMC_OFF);
    unsigned short* tcm  = (unsigned short*)(ws + TCM_OFF);
    unsigned short* snc  = (unsigned short*)(ws + SNC_OFF);
    unsigned short* part = (unsigned short*)(ws + PART_OFF);
    float* ps            = (float*)(ws + PS_OFF);
    float* ps2           = (float*)(ws + PS2_OFF);
    float* out           = (float*)d_out;

    // choose m-chunk count by available workspace: 32 chunks needs ~176 MB
    long need32 = PART_OFF + (long)Bb * 32 * Nn * VROWS * 2 + 2L * Bb * 32 * Nn * 4;
    int mcn = (ws_size >= (size_t)need32) ? 32 : 16;
    long zp_off = PART_OFF + (long)Bb * mcn * Nn * VROWS * 2;
    long pp_off = zp_off + (long)Bb * mcn * Nn * 4;
    float* zp = (float*)(ws + zp_off);
    float* pp = (float*)(ws + pp_off);

    k_prep_tgt<<<dim3(Mm / 64, Cc / 64, Bb), 256, 0, stream>>>(tgt_desc, tmc, tcm, ps, ps2);
    k_stats<<<dim3(Mm / 256, Bb), 256, 0, stream>>>(ps, ps2, tgt_coords, tgt_weights, scl, tcm);
    k_prep_src<<<dim3(Nn / 64, Cc / 64, Bb), 256, 0, stream>>>(src_desc, snc);
    k_main<<<dim3(mcn, Nn / 128, Bb), 256, 0, stream>>>(tmc, tcm, snc, scl, part, zp, pp, mcn);
    (void)hipMemsetAsync((char*)d_out + O_MAXSM * 4, 0, 2 * sizeof(float), stream);
    k_epi<<<dim3((Bb * Nn) / 4), 256, 0, stream>>>(part, zp, pp, out, mcn);
}

// Round 16
// 274.787 us; speedup vs baseline: 1.2203x; 1.0161x over previous
//
#include <hip/hip_runtime.h>
#include <hip/hip_bf16.h>

// ---------------- problem constants ----------------
#define Bb   2
#define Cc   256
#define Nn   1024
#define Mm   65536
#define VROWS 272         // 256 desc + 3 coords + 1 weight + ones + 11 pad
#define MSTEP 32

// workspace byte offsets (fixed part)
#define SCL_OFF  0L                               // B*M f32           (0.5 MB)
#define TMC_OFF  524288L                          // B*M*C bf16        (67 MB)   K: [b][m][c]
#define TCM_OFF  67633152L                        // B*272*M bf16      (71.3 MB) V: [b][row][m]
#define SNC_OFF  138936320L                       // B*N*C bf16        (1 MB)    Q^T: [b][n][c]
#define PART_OFF 139984896L                       // B*mcn*N*272 bf16  (runtime mcn)
// stats partials live in the part region (consumed before k_main writes part)
#define PS_OFF   PART_OFF                         // [B][4][M] f32 sums   (2 MB)
#define PS2_OFF  (PART_OFF + 2097152L)            // [B][4][M] f32 sumsq  (2 MB)

// output float offsets
#define O_COORD 0L
#define O_W     6144L
#define O_DESC  8192L
#define O_P2D   532480L
#define O_VALID 536576L
#define O_MAXSM 538624L

using f32x4 = __attribute__((ext_vector_type(4))) float;
using s16x8 = __attribute__((ext_vector_type(8))) short;

__device__ inline unsigned short f2bf(float x) {
    union { float f; unsigned int u; } v; v.f = x;
    unsigned int r = v.u + 0x7FFFu + ((v.u >> 16) & 1u);   // RNE
    return (unsigned short)(r >> 16);
}
__device__ inline float bf2f(unsigned short u) {
    union { unsigned int u; float f; } v; v.u = ((unsigned int)u) << 16;
    return v.f;
}
__device__ inline float exp2v(float x) {
    float r; asm("v_exp_f32 %0, %1" : "=v"(r) : "v"(x)); return r;
}
__device__ inline unsigned int cvtpk(float lo, float hi) {
    unsigned int r;
    asm("v_cvt_pk_bf16_f32 %0, %1, %2" : "=v"(r) : "v"(lo), "v"(hi));
    return r;
}

__device__ inline void gld_lds16(const unsigned short* g, unsigned short* l) {
    __builtin_amdgcn_global_load_lds(
        (const __attribute__((address_space(1))) unsigned int*)g,
        (__attribute__((address_space(3))) unsigned int*)l, 16, 0, 0);
}

// ------- prep A (vectorized): tgt_desc f32 -> tmc bf16 [b][m][c] + tcm bf16 [b][c][m],
//         plus per-(c-block, m) partial sums for the column stats.
// Tile 64c x 64m per block. Phase 1: float4 reads (1KB/wave), cvt_pk uint2 tcm
// writes, LDS staged [m][c] (transpose at store; 2-way banks = free), stats in
// registers reduced via shfl + small LDS. Phase 2: conflict-free scalar LDS
// reads -> tmc bf16 writes (128B segments), identical to the proven pattern.
__global__ void k_prep_tgt(const float* __restrict__ tgt,
                           unsigned short* __restrict__ tmc,
                           unsigned short* __restrict__ tcm,
                           float* __restrict__ ps,
                           float* __restrict__ ps2) {
    __shared__ float lds[64][65];                 // [m_local][c_local]
    __shared__ float smS[4][64], smQ[4][64];
    int b = blockIdx.z, cy = blockIdx.y, c0 = cy * 64;
    long m0 = (long)blockIdx.x * 64;
    int t = threadIdx.x, ty = t >> 6, lane = t & 63;
    int mq = lane & 15, cj = lane >> 4;

    float s4[4] = {0.f, 0.f, 0.f, 0.f}, q4[4] = {0.f, 0.f, 0.f, 0.f};
    #pragma unroll
    for (int k = 0; k < 4; ++k) {
        int cl = 16 * k + ty * 4 + cj;            // c within tile
        const float* gp = tgt + (long)(b * Cc + c0 + cl) * Mm + m0 + mq * 4;
        float4 v = *(const float4*)gp;
        s4[0] += v.x; s4[1] += v.y; s4[2] += v.z; s4[3] += v.w;
        q4[0] += v.x * v.x; q4[1] += v.y * v.y; q4[2] += v.z * v.z; q4[3] += v.w * v.w;
        uint2 u; u.x = cvtpk(v.x, v.y); u.y = cvtpk(v.z, v.w);
        *(uint2*)&tcm[((long)b * VROWS + c0 + cl) * Mm + m0 + mq * 4] = u;
        lds[mq * 4 + 0][cl] = v.x;
        lds[mq * 4 + 1][cl] = v.y;
        lds[mq * 4 + 2][cl] = v.z;
        lds[mq * 4 + 3][cl] = v.w;
    }
    // reduce over cj (4 lane-groups of 16) via shfl, then over ty via LDS
    #pragma unroll
    for (int j = 0; j < 4; ++j) {
        s4[j] += __shfl_xor(s4[j], 16); s4[j] += __shfl_xor(s4[j], 32);
        q4[j] += __shfl_xor(q4[j], 16); q4[j] += __shfl_xor(q4[j], 32);
    }
    if (lane < 16) {
        #pragma unroll
        for (int j = 0; j < 4; ++j) { smS[ty][mq * 4 + j] = s4[j]; smQ[ty][mq * 4 + j] = q4[j]; }
    }
    __syncthreads();
    if (ty == 0 && lane < 16) {
        float4 S, Q;
        float* Sp = (float*)&S; float* Qp = (float*)&Q;
        #pragma unroll
        for (int j = 0; j < 4; ++j) {
            Sp[j] = (smS[0][mq * 4 + j] + smS[1][mq * 4 + j]) + (smS[2][mq * 4 + j] + smS[3][mq * 4 + j]);
            Qp[j] = (smQ[0][mq * 4 + j] + smQ[1][mq * 4 + j]) + (smQ[2][mq * 4 + j] + smQ[3][mq * 4 + j]);
        }
        long o = ((long)b * 4 + cy) * Mm + m0 + mq * 4;
        *(float4*)&ps[o] = S;
        *(float4*)&ps2[o] = Q;
    }
    // phase 2: tmc transpose out of LDS (conflict-free: bank = (mi+lane)%32)
    #pragma unroll
    for (int k2 = 0; k2 < 16; ++k2) {
        int mi = 4 * k2 + ty;
        tmc[((long)b * Mm + m0 + mi) * Cc + c0 + lane] = f2bf(lds[mi][lane]);
    }
}

// ------- prep B: finish stats -> scl; write coords/weights/ones rows of V -------
__global__ void k_stats(const float* __restrict__ ps,
                        const float* __restrict__ ps2,
                        const float* __restrict__ coords,
                        const float* __restrict__ weights,
                        float* __restrict__ scl,
                        unsigned short* __restrict__ tcm) {
    int b = blockIdx.y;
    long m = (long)blockIdx.x * 256 + threadIdx.x;
    float s = 0.f, s2 = 0.f;
    #pragma unroll
    for (int k = 0; k < 4; ++k) {
        long o = ((long)b * 4 + k) * Mm + m;
        s += ps[o]; s2 += ps2[o];
    }
    float var = fmaxf((s2 - s * s * (1.0f / Cc)) * (1.0f / (Cc - 1)), 1e-20f);
    scl[(long)b * Mm + m] = 1.4426950408889634f * rsqrtf(var) * (1.0f / (Cc * 0.01f));
    unsigned short* vrow = tcm + ((long)b * VROWS + 256) * Mm + m;
    #pragma unroll
    for (int i = 0; i < 3; ++i) vrow[(long)i * Mm] = f2bf(coords[((long)b * 3 + i) * Mm + m]);
    vrow[3L * Mm] = f2bf(weights[(long)b * Mm + m]);
    vrow[4L * Mm] = 0x3F80;   // ones row (channel 260): Z comes out of the PV MFMA
    #pragma unroll
    for (int i = 5; i < 16; ++i) vrow[(long)i * Mm] = 0;
}

// ------- prep C: src_desc_norm f32 -> snc bf16 [b][n][c] -------
__global__ void k_prep_src(const float* __restrict__ src, unsigned short* __restrict__ snc) {
    __shared__ float lds[64][65];
    int b = blockIdx.z, c0 = blockIdx.y * 64, n0 = blockIdx.x * 64;
    int ty = threadIdx.x >> 6, tx = threadIdx.x & 63;
    #pragma unroll
    for (int k = 0; k < 16; ++k)
        lds[4 * k + ty][tx] = src[((long)b * Cc + c0 + 4 * k + ty) * Nn + n0 + tx];
    __syncthreads();
    #pragma unroll
    for (int k = 0; k < 16; ++k) {
        int ni = 4 * k + ty;
        snc[((long)b * Nn + n0 + ni) * Cc + c0 + tx] = f2bf(lds[tx][ni]);
    }
}

// ------- main fused kernel: 32 n per wave, 2 blocks per CU, reg-only P -------
// (unchanged from round 15 — validated best)
__global__ __launch_bounds__(256, 2) void k_main(const unsigned short* __restrict__ tmc,
                                                 const unsigned short* __restrict__ tcm,
                                                 const unsigned short* __restrict__ snc,
                                                 const float* __restrict__ scl,
                                                 unsigned short* __restrict__ part,
                                                 float* __restrict__ zp,
                                                 float* __restrict__ pp,
                                                 int mcn) {
    __shared__ __align__(16) unsigned short kb[2][8192];          // 32 KB
    __shared__ __align__(16) unsigned short vb[2][8704];          // 34 KB  total 66 KB

    int w = threadIdx.x >> 6, lane = threadIdx.x & 63;
    int l15 = lane & 15, lg = lane >> 4;
    int b = blockIdx.z, nt = blockIdx.y, mc = blockIdx.x;
    int nb = nt * 128 + w * 32;
    int mchunk = Mm / mcn;
    int nit = mchunk / MSTEP;
    long mbase = (long)mc * mchunk;

    // Q^T B-fragments for 2 n-subtiles (64 VGPR)
    s16x8 qf[2][8];
    #pragma unroll
    for (int st = 0; st < 2; ++st) {
        const unsigned short* qp = snc + ((long)b * Nn + nb + st * 16 + l15) * Cc + lg * 8;
        #pragma unroll
        for (int cc = 0; cc < 8; ++cc) qf[st][cc] = *(const s16x8*)(qp + cc * 32);
    }

    f32x4 acc[2][17];
    #pragma unroll
    for (int st = 0; st < 2; ++st)
        #pragma unroll
        for (int t = 0; t < 17; ++t) acc[st][t] = (f32x4){0.f, 0.f, 0.f, 0.f};
    float pmax[2] = {0.f, 0.f};

    // ---- staging: uniform bases (SGPR) + u32 element offsets (VGPR) ----
    const unsigned short* tmcb = tmc + (long)b * Mm * Cc;
    const unsigned short* tcmb = tcm + (long)b * VROWS * (long)Mm;
    unsigned koff[4];
    #pragma unroll
    for (int i = 0; i < 4; ++i) {
        int ins = w * 4 + i;                  // K instr 0..15, covers LDS rows 2*ins, 2*ins+1
        int a   = 2 * ins + (lane >> 5);      // LDS row
        int pa  = ((a >> 2) & 3) * 8 + ((a >> 4) << 2) + (a & 3);   // source global row
        int gs  = (lane & 31) ^ (a & 7);      // pre-swizzled 16B slot (keyed to LDS row)
        koff[i] = (unsigned)((mbase + pa) * Cc + gs * 8);
    }
    unsigned voff[5];
    int vj = ((lane & 3) ^ ((lane >> 3) & 3)) * 8;   // chunk-XOR pre-swizzle
    #pragma unroll
    for (int i = 0; i < 5; ++i) {
        int ins = (i < 4) ? (w * 4 + i) : 16;
        int row = ins * 16 + (lane >> 2);
        voff[i] = (unsigned)((long)row * Mm + mbase + vj);
    }

    const float* sclb = scl + (long)b * Mm;

    auto stage = [&](int d) {
        unsigned short* kd = kb[d];
        unsigned short* vd = vb[d];
        #pragma unroll
        for (int i = 0; i < 4; ++i) gld_lds16(tmcb + koff[i], kd + (w * 4 + i) * 512);
        #pragma unroll
        for (int i = 0; i < 4; ++i) gld_lds16(tcmb + voff[i], vd + (w * 4 + i) * 512);
        if (w == 3) gld_lds16(tcmb + voff[4], vd + 16 * 512);
        #pragma unroll
        for (int i = 0; i < 4; ++i) koff[i] += MSTEP * Cc;
        #pragma unroll
        for (int i = 0; i < 5; ++i) voff[i] += MSTEP;
    };

    int ksw = (l15 & 7) << 3;              // K read swizzle (elements)
    int vsw = (lg ^ ((l15 >> 1) & 3)) * 8; // V read chunk swizzle (elements)

    stage(0);
    __syncthreads();

    for (int s = 0; s < nit; ++s) {
        int cur = s & 1;
        if (s + 1 < nit) stage(cur ^ 1);
        const unsigned short* kbc = kb[cur];
        const unsigned short* vbc = vb[cur];
        long m0 = mbase + (long)s * MSTEP;
        // scl for D position (t,lg,r) = physical m = lg*8 + t*4 + r
        float4 sc0 = *(const float4*)(sclb + m0 + lg * 8);       // t=0
        float4 sc1 = *(const float4*)(sclb + m0 + lg * 8 + 4);   // t=1

        // ---- QK: 2 m-subtiles x 2 n-subtiles; P packed in registers ----
        unsigned int pwA[4], pwB[4];
        #pragma unroll
        for (int t = 0; t < 2; ++t) {
            f32x4 dA = (f32x4){0.f, 0.f, 0.f, 0.f};
            f32x4 dB = (f32x4){0.f, 0.f, 0.f, 0.f};
            const unsigned short* kr = kbc + (t * 16 + l15) * Cc;
            #pragma unroll
            for (int cc = 0; cc < 8; ++cc) {
                s16x8 kf = *(const s16x8*)(kr + ((cc * 32 + lg * 8) ^ ksw));
                dA = __builtin_amdgcn_mfma_f32_16x16x32_bf16(kf, qf[0][cc], dA, 0, 0, 0);
                dB = __builtin_amdgcn_mfma_f32_16x16x32_bf16(kf, qf[1][cc], dB, 0, 0, 0);
            }
            float4 sc = t ? sc1 : sc0;
            {
                float p0 = exp2v(dA.x * sc.x);
                float p1 = exp2v(dA.y * sc.y);
                float p2 = exp2v(dA.z * sc.z);
                float p3 = exp2v(dA.w * sc.w);
                pmax[0] = fmaxf(pmax[0], fmaxf(fmaxf(p0, p1), fmaxf(p2, p3)));
                pwA[t * 2 + 0] = cvtpk(p0, p1);
                pwA[t * 2 + 1] = cvtpk(p2, p3);
            }
            {
                float p0 = exp2v(dB.x * sc.x);
                float p1 = exp2v(dB.y * sc.y);
                float p2 = exp2v(dB.z * sc.z);
                float p3 = exp2v(dB.w * sc.w);
                pmax[1] = fmaxf(pmax[1], fmaxf(fmaxf(p0, p1), fmaxf(p2, p3)));
                pwB[t * 2 + 0] = cvtpk(p0, p1);
                pwB[t * 2 + 1] = cvtpk(p2, p3);
            }
        }
        union PU { unsigned int u[4]; s16x8 f; };
        PU puA, puB;
        #pragma unroll
        for (int j = 0; j < 4; ++j) { puA.u[j] = pwA[j]; puB.u[j] = pwB[j]; }
        s16x8 pfA = puA.f;
        s16x8 pfB = puB.f;

        // ---- PV: 17 output c-tiles; V-frag shared across both n-subtiles ----
        #pragma unroll
        for (int t = 0; t < 17; ++t) {
            s16x8 vf = *(const s16x8*)(vbc + (t * 16 + l15) * MSTEP + vsw);
            acc[0][t] = __builtin_amdgcn_mfma_f32_16x16x32_bf16(vf, pfA, acc[0][t], 0, 0, 0);
            acc[1][t] = __builtin_amdgcn_mfma_f32_16x16x32_bf16(vf, pfB, acc[1][t], 0, 0, 0);
        }
        __syncthreads();
    }

    // Z sits in acc[st][16].x on lanes lg==1 (channel 260 = ones row)
    #pragma unroll
    for (int st = 0; st < 2; ++st) {
        float pt = fmaxf(pmax[st], __shfl_xor(pmax[st], 16));
        pt = fmaxf(pt, __shfl_xor(pt, 32));
        long zi = ((long)(b * mcn + mc)) * Nn + nb + st * 16;
        if (lg == 1) zp[zi + l15] = acc[st][16].x;
        if (lane < 16) pp[zi + lane] = pt;
        unsigned short* po = part + (((long)(b * mcn + mc) * Nn) + nb + st * 16 + l15) * VROWS;
        #pragma unroll
        for (int t = 0; t < 17; ++t) {
            f32x4 a = acc[st][t];
            unsigned long long pk =
                (unsigned long long)cvtpk(a.x, a.y) | ((unsigned long long)cvtpk(a.z, a.w) << 32);
            *(unsigned long long*)&po[t * 16 + lg * 4] = pk;
        }
    }
}

// ------- epilogue: combine m-chunks, normalize, zn(descs), 2D projection, max_softmax -------
__global__ void k_epi(const unsigned short* __restrict__ part,
                      const float* __restrict__ zp,
                      const float* __restrict__ pp,
                      float* __restrict__ out,
                      int mcn) {
    int w = threadIdx.x >> 6, lane = threadIdx.x & 63;
    int bn = blockIdx.x * 4 + w;
    int b = bn >> 10, n = bn & 1023;

    float Z = 0.f, pm = 0.f;
    for (int mc = 0; mc < mcn; ++mc) {
        long zi = ((long)(b * mcn + mc)) * Nn + n;
        Z += zp[zi];
        pm = fmaxf(pm, pp[zi]);
    }
    float invZ = 1.0f / Z;

    float dv[4], s1 = 0.f, s2 = 0.f;
    #pragma unroll
    for (int k = 0; k < 4; ++k) {
        int c = lane + 64 * k;
        float s = 0.f;
        for (int mc = 0; mc < mcn; ++mc)
            s += bf2f(part[((long)(b * mcn + mc) * Nn + n) * VROWS + c]);
        float d = s * invZ;
        dv[k] = d; s1 += d; s2 += d * d;
    }
    #pragma unroll
    for (int off = 1; off < 64; off <<= 1) { s1 += __shfl_xor(s1, off); s2 += __shfl_xor(s2, off); }
    float mean = s1 * (1.0f / 256.0f);
    float var = fmaxf((s2 - 256.0f * mean * mean) * (1.0f / 255.0f), 1e-20f);
    float istd = 1.0f / sqrtf(var);
    #pragma unroll
    for (int k = 0; k < 4; ++k)
        out[O_DESC + ((long)b * Cc + lane + 64 * k) * Nn + n] = (dv[k] - mean) * istd;

    float ex = 0.f;
    if (lane < 4) {
        int c = 256 + lane;
        for (int mc = 0; mc < mcn; ++mc)
            ex += bf2f(part[((long)(b * mcn + mc) * Nn + n) * VROWS + c]);
        ex *= invZ;
    }
    float pc0 = __shfl(ex, 0), pc1 = __shfl(ex, 1), pc2 = __shfl(ex, 2), wv = __shfl(ex, 3);
    if (lane == 0) {
        out[O_COORD + ((long)b * 3 + 0) * Nn + n] = pc0;
        out[O_COORD + ((long)b * 3 + 1) * Nn + n] = pc1;
        out[O_COORD + ((long)b * 3 + 2) * Nn + n] = pc2;
        out[O_W + (long)b * Nn + n] = wv;
        const float cmin = 33.048f;                 // (256/2 - 0.5) * 0.2592
        out[O_P2D + ((long)b * Nn + n) * 2 + 0] = (cmin + pc1) * (1.0f / 0.2592f);
        out[O_P2D + ((long)b * Nn + n) * 2 + 1] = (cmin - pc0) * (1.0f / 0.2592f);
        out[O_VALID + (long)b * Nn + n] = 1.0f;
        atomicMax((unsigned int*)out + O_MAXSM + b, __float_as_uint(pm * invZ));
    }
}

extern "C" void kernel_launch(void* const* d_in, const int* in_sizes, int n_in,
                              void* d_out, int out_size, void* d_ws, size_t ws_size,
                              hipStream_t stream) {
    const float* tgt_coords  = (const float*)d_in[1];
    const float* tgt_weights = (const float*)d_in[3];
    const float* src_desc    = (const float*)d_in[5];
    const float* tgt_desc    = (const float*)d_in[6];

    char* ws = (char*)d_ws;
    float* scl           = (float*)(ws + SCL_OFF);
    unsigned short* tmc  = (unsigned short*)(ws + TMC_OFF);
    unsigned short* tcm  = (unsigned short*)(ws + TCM_OFF);
    unsigned short* snc  = (unsigned short*)(ws + SNC_OFF);
    unsigned short* part = (unsigned short*)(ws + PART_OFF);
    float* ps            = (float*)(ws + PS_OFF);
    float* ps2           = (float*)(ws + PS2_OFF);
    float* out           = (float*)d_out;

    // choose m-chunk count by available workspace: 32 chunks needs ~176 MB
    long need32 = PART_OFF + (long)Bb * 32 * Nn * VROWS * 2 + 2L * Bb * 32 * Nn * 4;
    int mcn = (ws_size >= (size_t)need32) ? 32 : 16;
    long zp_off = PART_OFF + (long)Bb * mcn * Nn * VROWS * 2;
    long pp_off = zp_off + (long)Bb * mcn * Nn * 4;
    float* zp = (float*)(ws + zp_off);
    float* pp = (float*)(ws + pp_off);

    k_prep_tgt<<<dim3(Mm / 64, Cc / 64, Bb), 256, 0, stream>>>(tgt_desc, tmc, tcm, ps, ps2);
    k_stats<<<dim3(Mm / 256, Bb), 256, 0, stream>>>(ps, ps2, tgt_coords, tgt_weights, scl, tcm);
    k_prep_src<<<dim3(Nn / 64, Cc / 64, Bb), 256, 0, stream>>>(src_desc, snc);
    k_main<<<dim3(mcn, Nn / 128, Bb), 256, 0, stream>>>(tmc, tcm, snc, scl, part, zp, pp, mcn);
    (void)hipMemsetAsync((char*)d_out + O_MAXSM * 4, 0, 2 * sizeof(float), stream);
    k_epi<<<dim3((Bb * Nn) / 4), 256, 0, stream>>>(part, zp, pp, out, mcn);
}

// Round 17
// 271.450 us; speedup vs baseline: 1.2353x; 1.0123x over previous
//
#include <hip/hip_runtime.h>
#include <hip/hip_bf16.h>

// ---------------- problem constants ----------------
#define Bb   2
#define Cc   256
#define Nn   1024
#define Mm   65536
#define VROWS 272         // 256 desc + 3 coords + 1 weight + ones + 11 pad
#define MSTEP 32

// workspace byte offsets (fixed part)
#define SCL_OFF  0L                               // B*M f32           (0.5 MB)
#define TMC_OFF  524288L                          // B*M*C bf16        (67 MB)   K: [b][m][c]
#define TCM_OFF  67633152L                        // B*272*M bf16      (71.3 MB) V: [b][row][m]
#define SNC_OFF  138936320L                       // B*N*C bf16        (1 MB)    Q^T: [b][n][c]
#define PART_OFF 139984896L                       // B*mcn*N*272 bf16  (runtime mcn)
// stats partials live in the part region (consumed before k_main writes part)
#define PS_OFF   PART_OFF                         // [B][4][M] f32 sums   (2 MB)
#define PS2_OFF  (PART_OFF + 2097152L)            // [B][4][M] f32 sumsq  (2 MB)

// output float offsets
#define O_COORD 0L
#define O_W     6144L
#define O_DESC  8192L
#define O_P2D   532480L
#define O_VALID 536576L
#define O_MAXSM 538624L

using f32x4 = __attribute__((ext_vector_type(4))) float;
using s16x8 = __attribute__((ext_vector_type(8))) short;

__device__ inline unsigned short f2bf(float x) {
    union { float f; unsigned int u; } v; v.f = x;
    unsigned int r = v.u + 0x7FFFu + ((v.u >> 16) & 1u);   // RNE
    return (unsigned short)(r >> 16);
}
__device__ inline float bf2f(unsigned short u) {
    union { unsigned int u; float f; } v; v.u = ((unsigned int)u) << 16;
    return v.f;
}
__device__ inline float exp2v(float x) {
    float r; asm("v_exp_f32 %0, %1" : "=v"(r) : "v"(x)); return r;
}
__device__ inline unsigned int cvtpk(float lo, float hi) {
    unsigned int r;
    asm("v_cvt_pk_bf16_f32 %0, %1, %2" : "=v"(r) : "v"(lo), "v"(hi));
    return r;
}

__device__ inline void gld_lds16(const unsigned short* g, unsigned short* l) {
    __builtin_amdgcn_global_load_lds(
        (const __attribute__((address_space(1))) unsigned int*)g,
        (__attribute__((address_space(3))) unsigned int*)l, 16, 0, 0);
}

// ------- prep A (vectorized): tgt_desc f32 -> tmc bf16 [b][m][c] + tcm bf16 [b][c][m],
//         plus per-(c-block, m) partial sums for the column stats. -------
__global__ void k_prep_tgt(const float* __restrict__ tgt,
                           unsigned short* __restrict__ tmc,
                           unsigned short* __restrict__ tcm,
                           float* __restrict__ ps,
                           float* __restrict__ ps2) {
    __shared__ float lds[64][65];                 // [m_local][c_local]
    __shared__ float smS[4][64], smQ[4][64];
    int b = blockIdx.z, cy = blockIdx.y, c0 = cy * 64;
    long m0 = (long)blockIdx.x * 64;
    int t = threadIdx.x, ty = t >> 6, lane = t & 63;
    int mq = lane & 15, cj = lane >> 4;

    float s4[4] = {0.f, 0.f, 0.f, 0.f}, q4[4] = {0.f, 0.f, 0.f, 0.f};
    #pragma unroll
    for (int k = 0; k < 4; ++k) {
        int cl = 16 * k + ty * 4 + cj;            // c within tile
        const float* gp = tgt + (long)(b * Cc + c0 + cl) * Mm + m0 + mq * 4;
        float4 v = *(const float4*)gp;
        s4[0] += v.x; s4[1] += v.y; s4[2] += v.z; s4[3] += v.w;
        q4[0] += v.x * v.x; q4[1] += v.y * v.y; q4[2] += v.z * v.z; q4[3] += v.w * v.w;
        uint2 u; u.x = cvtpk(v.x, v.y); u.y = cvtpk(v.z, v.w);
        *(uint2*)&tcm[((long)b * VROWS + c0 + cl) * Mm + m0 + mq * 4] = u;
        lds[mq * 4 + 0][cl] = v.x;
        lds[mq * 4 + 1][cl] = v.y;
        lds[mq * 4 + 2][cl] = v.z;
        lds[mq * 4 + 3][cl] = v.w;
    }
    #pragma unroll
    for (int j = 0; j < 4; ++j) {
        s4[j] += __shfl_xor(s4[j], 16); s4[j] += __shfl_xor(s4[j], 32);
        q4[j] += __shfl_xor(q4[j], 16); q4[j] += __shfl_xor(q4[j], 32);
    }
    if (lane < 16) {
        #pragma unroll
        for (int j = 0; j < 4; ++j) { smS[ty][mq * 4 + j] = s4[j]; smQ[ty][mq * 4 + j] = q4[j]; }
    }
    __syncthreads();
    if (ty == 0 && lane < 16) {
        float4 S, Q;
        float* Sp = (float*)&S; float* Qp = (float*)&Q;
        #pragma unroll
        for (int j = 0; j < 4; ++j) {
            Sp[j] = (smS[0][mq * 4 + j] + smS[1][mq * 4 + j]) + (smS[2][mq * 4 + j] + smS[3][mq * 4 + j]);
            Qp[j] = (smQ[0][mq * 4 + j] + smQ[1][mq * 4 + j]) + (smQ[2][mq * 4 + j] + smQ[3][mq * 4 + j]);
        }
        long o = ((long)b * 4 + cy) * Mm + m0 + mq * 4;
        *(float4*)&ps[o] = S;
        *(float4*)&ps2[o] = Q;
    }
    #pragma unroll
    for (int k2 = 0; k2 < 16; ++k2) {
        int mi = 4 * k2 + ty;
        tmc[((long)b * Mm + m0 + mi) * Cc + c0 + lane] = f2bf(lds[mi][lane]);
    }
}

// ------- prep B: finish stats -> scl; write coords/weights/ones rows of V -------
__global__ void k_stats(const float* __restrict__ ps,
                        const float* __restrict__ ps2,
                        const float* __restrict__ coords,
                        const float* __restrict__ weights,
                        float* __restrict__ scl,
                        unsigned short* __restrict__ tcm) {
    int b = blockIdx.y;
    long m = (long)blockIdx.x * 256 + threadIdx.x;
    float s = 0.f, s2 = 0.f;
    #pragma unroll
    for (int k = 0; k < 4; ++k) {
        long o = ((long)b * 4 + k) * Mm + m;
        s += ps[o]; s2 += ps2[o];
    }
    float var = fmaxf((s2 - s * s * (1.0f / Cc)) * (1.0f / (Cc - 1)), 1e-20f);
    scl[(long)b * Mm + m] = 1.4426950408889634f * rsqrtf(var) * (1.0f / (Cc * 0.01f));
    unsigned short* vrow = tcm + ((long)b * VROWS + 256) * Mm + m;
    #pragma unroll
    for (int i = 0; i < 3; ++i) vrow[(long)i * Mm] = f2bf(coords[((long)b * 3 + i) * Mm + m]);
    vrow[3L * Mm] = f2bf(weights[(long)b * Mm + m]);
    vrow[4L * Mm] = 0x3F80;   // ones row (channel 260): Z comes out of the PV MFMA
    #pragma unroll
    for (int i = 5; i < 16; ++i) vrow[(long)i * Mm] = 0;
}

// ------- prep C: src_desc_norm f32 -> snc bf16 [b][n][c] -------
__global__ void k_prep_src(const float* __restrict__ src, unsigned short* __restrict__ snc) {
    __shared__ float lds[64][65];
    int b = blockIdx.z, c0 = blockIdx.y * 64, n0 = blockIdx.x * 64;
    int ty = threadIdx.x >> 6, tx = threadIdx.x & 63;
    #pragma unroll
    for (int k = 0; k < 16; ++k)
        lds[4 * k + ty][tx] = src[((long)b * Cc + c0 + 4 * k + ty) * Nn + n0 + tx];
    __syncthreads();
    #pragma unroll
    for (int k = 0; k < 16; ++k) {
        int ni = 4 * k + ty;
        snc[((long)b * Nn + n0 + ni) * Cc + c0 + tx] = f2bf(lds[tx][ni]);
    }
}

// ------- main fused kernel: 32 n per wave, 2 blocks per CU, reg-only P,
//         T5 s_setprio around the MFMA clusters (pays with 2 drifting blocks/CU) -------
__global__ __launch_bounds__(256, 2) void k_main(const unsigned short* __restrict__ tmc,
                                                 const unsigned short* __restrict__ tcm,
                                                 const unsigned short* __restrict__ snc,
                                                 const float* __restrict__ scl,
                                                 unsigned short* __restrict__ part,
                                                 float* __restrict__ zp,
                                                 float* __restrict__ pp,
                                                 int mcn) {
    __shared__ __align__(16) unsigned short kb[2][8192];          // 32 KB
    __shared__ __align__(16) unsigned short vb[2][8704];          // 34 KB  total 66 KB

    int w = threadIdx.x >> 6, lane = threadIdx.x & 63;
    int l15 = lane & 15, lg = lane >> 4;
    int b = blockIdx.z, nt = blockIdx.y, mc = blockIdx.x;
    int nb = nt * 128 + w * 32;
    int mchunk = Mm / mcn;
    int nit = mchunk / MSTEP;
    long mbase = (long)mc * mchunk;

    // Q^T B-fragments for 2 n-subtiles (64 VGPR)
    s16x8 qf[2][8];
    #pragma unroll
    for (int st = 0; st < 2; ++st) {
        const unsigned short* qp = snc + ((long)b * Nn + nb + st * 16 + l15) * Cc + lg * 8;
        #pragma unroll
        for (int cc = 0; cc < 8; ++cc) qf[st][cc] = *(const s16x8*)(qp + cc * 32);
    }

    f32x4 acc[2][17];
    #pragma unroll
    for (int st = 0; st < 2; ++st)
        #pragma unroll
        for (int t = 0; t < 17; ++t) acc[st][t] = (f32x4){0.f, 0.f, 0.f, 0.f};
    float pmax[2] = {0.f, 0.f};

    // ---- staging: uniform bases (SGPR) + u32 element offsets (VGPR) ----
    const unsigned short* tmcb = tmc + (long)b * Mm * Cc;
    const unsigned short* tcmb = tcm + (long)b * VROWS * (long)Mm;
    unsigned koff[4];
    #pragma unroll
    for (int i = 0; i < 4; ++i) {
        int ins = w * 4 + i;                  // K instr 0..15, covers LDS rows 2*ins, 2*ins+1
        int a   = 2 * ins + (lane >> 5);      // LDS row
        int pa  = ((a >> 2) & 3) * 8 + ((a >> 4) << 2) + (a & 3);   // source global row (perm)
        int gs  = (lane & 31) ^ (a & 7);      // pre-swizzled 16B slot (keyed to LDS row)
        koff[i] = (unsigned)((mbase + pa) * Cc + gs * 8);
    }
    unsigned voff[5];
    int vj = ((lane & 3) ^ ((lane >> 3) & 3)) * 8;   // chunk-XOR pre-swizzle
    #pragma unroll
    for (int i = 0; i < 5; ++i) {
        int ins = (i < 4) ? (w * 4 + i) : 16;
        int row = ins * 16 + (lane >> 2);
        voff[i] = (unsigned)((long)row * Mm + mbase + vj);
    }

    const float* sclb = scl + (long)b * Mm;

    auto stage = [&](int d) {
        unsigned short* kd = kb[d];
        unsigned short* vd = vb[d];
        #pragma unroll
        for (int i = 0; i < 4; ++i) gld_lds16(tmcb + koff[i], kd + (w * 4 + i) * 512);
        #pragma unroll
        for (int i = 0; i < 4; ++i) gld_lds16(tcmb + voff[i], vd + (w * 4 + i) * 512);
        if (w == 3) gld_lds16(tcmb + voff[4], vd + 16 * 512);
        #pragma unroll
        for (int i = 0; i < 4; ++i) koff[i] += MSTEP * Cc;
        #pragma unroll
        for (int i = 0; i < 5; ++i) voff[i] += MSTEP;
    };

    int ksw = (l15 & 7) << 3;              // K read swizzle (elements)
    int vsw = (lg ^ ((l15 >> 1) & 3)) * 8; // V read chunk swizzle (elements)

    stage(0);
    __syncthreads();

    for (int s = 0; s < nit; ++s) {
        int cur = s & 1;
        if (s + 1 < nit) stage(cur ^ 1);
        const unsigned short* kbc = kb[cur];
        const unsigned short* vbc = vb[cur];
        long m0 = mbase + (long)s * MSTEP;
        // scl for D position (t,lg,r) = physical m = lg*8 + t*4 + r
        float4 sc0 = *(const float4*)(sclb + m0 + lg * 8);       // t=0
        float4 sc1 = *(const float4*)(sclb + m0 + lg * 8 + 4);   // t=1

        // ---- QK: 2 m-subtiles x 2 n-subtiles; P packed in registers ----
        unsigned int pwA[4], pwB[4];
        #pragma unroll
        for (int t = 0; t < 2; ++t) {
            f32x4 dA = (f32x4){0.f, 0.f, 0.f, 0.f};
            f32x4 dB = (f32x4){0.f, 0.f, 0.f, 0.f};
            const unsigned short* kr = kbc + (t * 16 + l15) * Cc;
            __builtin_amdgcn_s_setprio(1);
            #pragma unroll
            for (int cc = 0; cc < 8; ++cc) {
                s16x8 kf = *(const s16x8*)(kr + ((cc * 32 + lg * 8) ^ ksw));
                dA = __builtin_amdgcn_mfma_f32_16x16x32_bf16(kf, qf[0][cc], dA, 0, 0, 0);
                dB = __builtin_amdgcn_mfma_f32_16x16x32_bf16(kf, qf[1][cc], dB, 0, 0, 0);
            }
            __builtin_amdgcn_s_setprio(0);
            float4 sc = t ? sc1 : sc0;
            {
                float p0 = exp2v(dA.x * sc.x);
                float p1 = exp2v(dA.y * sc.y);
                float p2 = exp2v(dA.z * sc.z);
                float p3 = exp2v(dA.w * sc.w);
                pmax[0] = fmaxf(pmax[0], fmaxf(fmaxf(p0, p1), fmaxf(p2, p3)));
                pwA[t * 2 + 0] = cvtpk(p0, p1);
                pwA[t * 2 + 1] = cvtpk(p2, p3);
            }
            {
                float p0 = exp2v(dB.x * sc.x);
                float p1 = exp2v(dB.y * sc.y);
                float p2 = exp2v(dB.z * sc.z);
                float p3 = exp2v(dB.w * sc.w);
                pmax[1] = fmaxf(pmax[1], fmaxf(fmaxf(p0, p1), fmaxf(p2, p3)));
                pwB[t * 2 + 0] = cvtpk(p0, p1);
                pwB[t * 2 + 1] = cvtpk(p2, p3);
            }
        }
        union PU { unsigned int u[4]; s16x8 f; };
        PU puA, puB;
        #pragma unroll
        for (int j = 0; j < 4; ++j) { puA.u[j] = pwA[j]; puB.u[j] = pwB[j]; }
        s16x8 pfA = puA.f;
        s16x8 pfB = puB.f;

        // ---- PV: 17 output c-tiles; V-frag shared across both n-subtiles ----
        __builtin_amdgcn_s_setprio(1);
        #pragma unroll
        for (int t = 0; t < 17; ++t) {
            s16x8 vf = *(const s16x8*)(vbc + (t * 16 + l15) * MSTEP + vsw);
            acc[0][t] = __builtin_amdgcn_mfma_f32_16x16x32_bf16(vf, pfA, acc[0][t], 0, 0, 0);
            acc[1][t] = __builtin_amdgcn_mfma_f32_16x16x32_bf16(vf, pfB, acc[1][t], 0, 0, 0);
        }
        __builtin_amdgcn_s_setprio(0);
        __syncthreads();
    }

    // Z sits in acc[st][16].x on lanes lg==1 (channel 260 = ones row)
    #pragma unroll
    for (int st = 0; st < 2; ++st) {
        float pt = fmaxf(pmax[st], __shfl_xor(pmax[st], 16));
        pt = fmaxf(pt, __shfl_xor(pt, 32));
        long zi = ((long)(b * mcn + mc)) * Nn + nb + st * 16;
        if (lg == 1) zp[zi + l15] = acc[st][16].x;
        if (lane < 16) pp[zi + lane] = pt;
        unsigned short* po = part + (((long)(b * mcn + mc) * Nn) + nb + st * 16 + l15) * VROWS;
        #pragma unroll
        for (int t = 0; t < 17; ++t) {
            f32x4 a = acc[st][t];
            unsigned long long pk =
                (unsigned long long)cvtpk(a.x, a.y) | ((unsigned long long)cvtpk(a.z, a.w) << 32);
            *(unsigned long long*)&po[t * 16 + lg * 4] = pk;
        }
    }
}

// ------- epilogue: combine m-chunks, normalize, zn(descs), 2D projection, max_softmax -------
__global__ void k_epi(const unsigned short* __restrict__ part,
                      const float* __restrict__ zp,
                      const float* __restrict__ pp,
                      float* __restrict__ out,
                      int mcn) {
    int w = threadIdx.x >> 6, lane = threadIdx.x & 63;
    int bn = blockIdx.x * 4 + w;
    int b = bn >> 10, n = bn & 1023;

    float Z = 0.f, pm = 0.f;
    for (int mc = 0; mc < mcn; ++mc) {
        long zi = ((long)(b * mcn + mc)) * Nn + n;
        Z += zp[zi];
        pm = fmaxf(pm, pp[zi]);
    }
    float invZ = 1.0f / Z;

    float dv[4], s1 = 0.f, s2 = 0.f;
    #pragma unroll
    for (int k = 0; k < 4; ++k) {
        int c = lane + 64 * k;
        float s = 0.f;
        for (int mc = 0; mc < mcn; ++mc)
            s += bf2f(part[((long)(b * mcn + mc) * Nn + n) * VROWS + c]);
        float d = s * invZ;
        dv[k] = d; s1 += d; s2 += d * d;
    }
    #pragma unroll
    for (int off = 1; off < 64; off <<= 1) { s1 += __shfl_xor(s1, off); s2 += __shfl_xor(s2, off); }
    float mean = s1 * (1.0f / 256.0f);
    float var = fmaxf((s2 - 256.0f * mean * mean) * (1.0f / 255.0f), 1e-20f);
    float istd = 1.0f / sqrtf(var);
    #pragma unroll
    for (int k = 0; k < 4; ++k)
        out[O_DESC + ((long)b * Cc + lane + 64 * k) * Nn + n] = (dv[k] - mean) * istd;

    float ex = 0.f;
    if (lane < 4) {
        int c = 256 + lane;
        for (int mc = 0; mc < mcn; ++mc)
            ex += bf2f(part[((long)(b * mcn + mc) * Nn + n) * VROWS + c]);
        ex *= invZ;
    }
    float pc0 = __shfl(ex, 0), pc1 = __shfl(ex, 1), pc2 = __shfl(ex, 2), wv = __shfl(ex, 3);
    if (lane == 0) {
        out[O_COORD + ((long)b * 3 + 0) * Nn + n] = pc0;
        out[O_COORD + ((long)b * 3 + 1) * Nn + n] = pc1;
        out[O_COORD + ((long)b * 3 + 2) * Nn + n] = pc2;
        out[O_W + (long)b * Nn + n] = wv;
        const float cmin = 33.048f;                 // (256/2 - 0.5) * 0.2592
        out[O_P2D + ((long)b * Nn + n) * 2 + 0] = (cmin + pc1) * (1.0f / 0.2592f);
        out[O_P2D + ((long)b * Nn + n) * 2 + 1] = (cmin - pc0) * (1.0f / 0.2592f);
        out[O_VALID + (long)b * Nn + n] = 1.0f;
        atomicMax((unsigned int*)out + O_MAXSM + b, __float_as_uint(pm * invZ));
    }
}

extern "C" void kernel_launch(void* const* d_in, const int* in_sizes, int n_in,
                              void* d_out, int out_size, void* d_ws, size_t ws_size,
                              hipStream_t stream) {
    const float* tgt_coords  = (const float*)d_in[1];
    const float* tgt_weights = (const float*)d_in[3];
    const float* src_desc    = (const float*)d_in[5];
    const float* tgt_desc    = (const float*)d_in[6];

    char* ws = (char*)d_ws;
    float* scl           = (float*)(ws + SCL_OFF);
    unsigned short* tmc  = (unsigned short*)(ws + TMC_OFF);
    unsigned short* tcm  = (unsigned short*)(ws + TCM_OFF);
    unsigned short* snc  = (unsigned short*)(ws + SNC_OFF);
    unsigned short* part = (unsigned short*)(ws + PART_OFF);
    float* ps            = (float*)(ws + PS_OFF);
    float* ps2           = (float*)(ws + PS2_OFF);
    float* out           = (float*)d_out;

    // choose m-chunk count by available workspace: 32 chunks needs ~176 MB
    long need32 = PART_OFF + (long)Bb * 32 * Nn * VROWS * 2 + 2L * Bb * 32 * Nn * 4;
    int mcn = (ws_size >= (size_t)need32) ? 32 : 16;
    long zp_off = PART_OFF + (long)Bb * mcn * Nn * VROWS * 2;
    long pp_off = zp_off + (long)Bb * mcn * Nn * 4;
    float* zp = (float*)(ws + zp_off);
    float* pp = (float*)(ws + pp_off);

    k_prep_tgt<<<dim3(Mm / 64, Cc / 64, Bb), 256, 0, stream>>>(tgt_desc, tmc, tcm, ps, ps2);
    k_stats<<<dim3(Mm / 256, Bb), 256, 0, stream>>>(ps, ps2, tgt_coords, tgt_weights, scl, tcm);
    k_prep_src<<<dim3(Nn / 64, Cc / 64, Bb), 256, 0, stream>>>(src_desc, snc);
    k_main<<<dim3(mcn, Nn / 128, Bb), 256, 0, stream>>>(tmc, tcm, snc, scl, part, zp, pp, mcn);
    (void)hipMemsetAsync((char*)d_out + O_MAXSM * 4, 0, 2 * sizeof(float), stream);
    k_epi<<<dim3((Bb * Nn) / 4), 256, 0, stream>>>(part, zp, pp, out, mcn);
}